// Round 12
// baseline (497.640 us; speedup 1.0000x reference)
//
#include <hip/hip_runtime.h>
#include <hip/hip_bf16.h>
#include <hip/hip_fp16.h>
#include <math.h>

#define NPIX   262144          // 512*512
#define NP     4194304         // 16*512*512
#define NBINS  8192
#define HSUB   16
#define RB     8               // output rows per block in fused PD kernel
#define SIG    0.125f
#define TAUC   0.125f
#define ALPHAC 0.15f
#define MUC    10.0f
#define EPSC   1e-6f
#define NEGINF -3.4e38f
#define IVT    (1.0f / (1.0f + TAUC))

// ---------- helpers ----------
__device__ __forceinline__ void cvt8h(float4 raw, float* d) {
    const __half2* h = (const __half2*)&raw;
#pragma unroll
    for (int j = 0; j < 4; ++j) {
        float2 f = __half22float2(h[j]);
        d[2 * j] = f.x; d[2 * j + 1] = f.y;
    }
}
__device__ __forceinline__ void ld8h(const __half* p, float* d) {
    cvt8h(*(const float4*)p, d);
}
__device__ __forceinline__ float4 pk8h(const float* s) {
    float4 r; __half2* h = (__half2*)&r;
#pragma unroll
    for (int j = 0; j < 4; ++j) h[j] = __floats2half2_rn(s[2 * j], s[2 * j + 1]);
    return r;
}
__device__ __forceinline__ float bnd(float d, float inv) {
    return ALPHAC * (1.f + MUC * __expf(-fabsf(d) * inv));
}
__device__ __forceinline__ float clmp(float v, float b) {
    return fminf(fmaxf(v, -b), b);
}
__device__ __forceinline__ float rth(float v) {     // fp16 round-trip
    return __half2float(__float2half_rn(v));
}

// ================= POOLING =================

// horizontal 31-max, 3-phase vHGW; fp16 output.
__global__ __launch_bounds__(512) void hpass3_k(const float* __restrict__ Iy,
                                                __half* __restrict__ H) {
    __shared__ float rowbuf[8][512];
    __shared__ float PB[8][512];
    __shared__ float SB[8][512];
    int tid = threadIdx.x;
    int plane = blockIdx.y;
    int y0 = blockIdx.x * 8;

#pragma unroll
    for (int q = 0; q < 2; ++q) {
        int idx = q * 512 + tid;
        int r = idx >> 7;
        int x4 = (idx & 127) << 2;
        float4 v;
        if (plane < 16) {
            v = *(const float4*)(Iy + (size_t)(plane * 3) * NPIX + (size_t)(y0 + r) * 512 + x4);
        } else {
            int b = plane - 16;
            float4 g = *(const float4*)(Iy + ((size_t)(b * 3) + 1) * NPIX + (size_t)(y0 + r) * 512 + x4);
            float4 bb = *(const float4*)(Iy + ((size_t)(b * 3) + 2) * NPIX + (size_t)(y0 + r) * 512 + x4);
            v = make_float4(fmaxf(g.x, bb.x), fmaxf(g.y, bb.y), fmaxf(g.z, bb.z), fmaxf(g.w, bb.w));
        }
        *(float4*)(&rowbuf[r][x4]) = v;
    }
    __syncthreads();

    if (tid < 272) {
        int type = tid / 136;
        int rem = tid % 136;
        int r = rem / 17;
        int seg = rem % 17;
        int s0 = seg * 31;
        if (type == 0) {
            float run = rowbuf[r][s0];
            PB[r][s0] = run;
            for (int j = 1; j < 31; ++j) {
                int idx = s0 + j;
                if (idx < 512) { run = fmaxf(run, rowbuf[r][idx]); PB[r][idx] = run; }
            }
        } else {
            int s1 = min(s0 + 30, 511);
            float run = rowbuf[r][s1];
            SB[r][s1] = run;
            for (int j = s1 - 1; j >= s0; --j) { run = fmaxf(run, rowbuf[r][j]); SB[r][j] = run; }
        }
    }
    __syncthreads();

    int x = tid, a = x - 15, bc = x + 15;
#pragma unroll
    for (int r = 0; r < 8; ++r) {
        float o;
        if (a < 0)        o = PB[r][bc];
        else if (bc > 511) o = fmaxf(SB[r][a], PB[r][511]);
        else              o = fmaxf(SB[r][a], PB[r][bc]);
        H[(size_t)plane * NPIX + (size_t)(y0 + r) * 512 + x] = __float2half_rn(o);
    }
}

// vertical 31-max, one plane x one segment per block. grid (8, 17, 32), block 64.
__global__ __launch_bounds__(64) void vpass2h_k(const __half* __restrict__ H,
                                                __half* __restrict__ V) {
    int x = blockIdx.x * 64 + threadIdx.x;
    int s = blockIdx.y;                 // 0..16
    const __half* in = H + (size_t)blockIdx.z * NPIX;
    __half*      out = V + (size_t)blockIdx.z * NPIX;
    int s0 = s * 31;

    float Sprev[31];
    if (s > 0) {
        int p0 = s0 - 31;
        float v[31];
#pragma unroll
        for (int j = 0; j < 31; ++j) v[j] = __half2float(in[(size_t)(p0 + j) * 512 + x]);
        float acc = NEGINF;
#pragma unroll
        for (int j = 30; j >= 0; --j) { acc = fmaxf(acc, v[j]); Sprev[j] = acc; }
    } else {
#pragma unroll
        for (int j = 0; j < 31; ++j) Sprev[j] = NEGINF;
    }

    float P = NEGINF;
#pragma unroll
    for (int r = 0; r < 31; ++r) {
        float vv = (s0 + r < 512) ? __half2float(in[(size_t)(s0 + r) * 512 + x]) : NEGINF;
        P = fmaxf(P, vv);
        int i = s0 + r - 15;
        if (i >= 0 && i <= 511) {
            int a = s0 + r - 30;
            float o;
            if (a < 0)       o = P;
            else if (r == 30) o = P;
            else              o = fmaxf(Sprev[r + 1], P);
            out[(size_t)i * 512 + x] = __float2half_rn(o);
        }
    }
}

// combine: xb = |vR - vM| + R, 8 px/thread
__global__ __launch_bounds__(256) void combineh_k(const __half* __restrict__ V,
                                                  const float* __restrict__ Iy,
                                                  __half* __restrict__ xb) {
    size_t i = ((size_t)blockIdx.x * 256 + threadIdx.x) * 8;
    int b = (int)(i >> 18);
    size_t off = i & (NPIX - 1);
    float vr[8], vm[8];
    ld8h(V + (size_t)b * NPIX + off, vr);
    ld8h(V + (size_t)(16 + b) * NPIX + off, vm);
    const float* R = Iy + (size_t)(b * 3) * NPIX + off;
    float4 r0 = *(const float4*)R;
    float4 r1 = *(const float4*)(R + 4);
    float rr[8] = {r0.x, r0.y, r0.z, r0.w, r1.x, r1.y, r1.z, r1.w};
    float a[8];
#pragma unroll
    for (int j = 0; j < 8; ++j) a[j] = fabsf(vr[j] - vm[j]) + rr[j];
    *(float4*)(xb + i) = pk8h(a);
}

// ================= HISTOGRAM / QUANTILE =================

__global__ __launch_bounds__(1024) void hist2_k(const __half* __restrict__ v,
                                                int* __restrict__ hist) {
    __shared__ int lh[NBINS];
    int s = blockIdx.x, b = blockIdx.y, tid = threadIdx.x;
    for (int i = tid; i < NBINS; i += 1024) lh[i] = 0;
    __syncthreads();
    const __half* p = v + (size_t)b * NPIX + (size_t)s * (NPIX / HSUB);
    for (int i = tid; i < NPIX / HSUB; i += 1024) {
        int bin = (int)(__half2float(p[i]) * (NBINS * 0.5f));
        bin = min(max(bin, 0), NBINS - 1);
        atomicAdd(&lh[bin], 1);
    }
    __syncthreads();
    for (int i = tid; i < NBINS; i += 1024) {
        int c = lh[i];
        if (c) atomicAdd(&hist[b * NBINS + i], c);
    }
}

__global__ __launch_bounds__(1024) void gradhisth_k(const __half* __restrict__ nh,
                                                    int* __restrict__ hist) {
    __shared__ int lh[NBINS];
    int s = blockIdx.x, b = blockIdx.y, tid = threadIdx.x;
    for (int i = tid; i < NBINS; i += 1024) lh[i] = 0;
    __syncthreads();
    const __half* p = nh + (size_t)b * NPIX;
    int base = s * (NPIX / HSUB);
    for (int ii = tid; ii < NPIX / HSUB; ii += 1024) {
        int i = base + ii;
        float c = __half2float(p[i]);
        int x = i & 511, y = i >> 9;
        float dx = (x < 511) ? __half2float(p[i + 1])   - c : 0.f;
        float dy = (y < 511) ? __half2float(p[i + 512]) - c : 0.f;
        float gm = sqrtf(dx * dx + dy * dy + EPSC);
        int bin = (int)(gm * (NBINS * 0.5f));
        bin = min(max(bin, 0), NBINS - 1);
        atomicAdd(&lh[bin], 1);
    }
    __syncthreads();
    for (int i = tid; i < NBINS; i += 1024) {
        int c = lh[i];
        if (c) atomicAdd(&hist[b * NBINS + i], c);
    }
}

__global__ __launch_bounds__(1024) void quant2_k(const int* __restrict__ hist,
                                                 float* __restrict__ scal,
                                                 float q0, float q1, int s0, int s1) {
    __shared__ int csum[1025];
    __shared__ int wsum[16];
    int b = blockIdx.x, tid = threadIdx.x;
    const int* h = hist + b * NBINS;
    int s = 0;
#pragma unroll
    for (int j = 0; j < NBINS / 1024; ++j) s += h[tid * (NBINS / 1024) + j];

    int lane = tid & 63, wave = tid >> 6;
    int v = s;
#pragma unroll
    for (int off = 1; off < 64; off <<= 1) {
        int n = __shfl_up(v, off, 64);
        if (lane >= off) v += n;
    }
    if (lane == 63) wsum[wave] = v;
    __syncthreads();
    if (wave == 0 && lane < 16) {
        int w = wsum[lane];
#pragma unroll
        for (int off = 1; off < 16; off <<= 1) {
            int n = __shfl_up(w, off, 64);
            if (lane >= off) w += n;
        }
        wsum[lane] = w;
    }
    __syncthreads();
    int incl = v + (wave > 0 ? wsum[wave - 1] : 0);
    csum[tid + 1] = incl;
    if (tid == 0) csum[0] = 0;
    __syncthreads();

#pragma unroll
    for (int pass = 0; pass < 2; ++pass) {
        int slot = pass ? s1 : s0;
        if (slot < 0) continue;
        float q = pass ? q1 : q0;
        float t = q * (float)(NPIX - 1);
        if ((float)csum[tid] <= t && (float)csum[tid + 1] > t) {
            const int per = NBINS / 1024;
            int cb = csum[tid];
            int bin = tid * per;
            int hv = 1;
            for (int j = 0; j < per; ++j) {
                hv = h[tid * per + j];
                if ((float)(cb + hv) > t) { bin = tid * per + j; break; }
                cb += hv;
            }
            float k = t - (float)cb;
            scal[b * 4 + slot] = ((float)bin + (k + 0.5f) / (float)hv) * (2.0f / NBINS);
        }
    }
}

// ---------------- N_hat (fp16) from xb (fp16), 8 px/thread ----------------
__global__ __launch_bounds__(256) void nhat2h_k(const __half* __restrict__ xb,
                                                const float* __restrict__ scal,
                                                __half* __restrict__ nhh) {
    size_t i = ((size_t)blockIdx.x * 256 + threadIdx.x) * 8;
    int b = (int)(i >> 18);
    float lo = scal[b * 4 + 0], hi = scal[b * 4 + 1];
    float inv = 1.0f / (hi - lo + EPSC);
    float v[8]; ld8h(xb + i, v);
    float a[8];
#pragma unroll
    for (int j = 0; j < 8; ++j)
        a[j] = fminf(fmaxf((v[j] - lo) * inv, 0.f), 1.f);
    *(float4*)(nhh + i) = pk8h(a);
}

// ================= FUSED 2-ITERATION PD KERNEL (55 KB LDS, 3 barriers) =======
// Phases: 0 (stage) / A (p^1) / B (u^1) / C' (p^2 + u^2 fused; py^2-upper
// recomputed bit-identically per sub, px^2-left via wave shfl).
__global__ __launch_bounds__(256) void pdf2_k(const __half* __restrict__ u,
                                              const __half* __restrict__ up,
                                              const __half* __restrict__ pxO,
                                              const __half* __restrict__ pyO,
                                              __half* __restrict__ pxN,
                                              __half* __restrict__ pyN,
                                              const __half* __restrict__ nh,
                                              const float* __restrict__ scal,
                                              __half* __restrict__ u1g,
                                              __half* __restrict__ u2g,
                                              float* __restrict__ outF,
                                              int last) {
    __shared__ __align__(16) char smem[56320];              // 55 KB
    __half (*ubar0h)[512] = (__half(*)[512])smem;           // 12 rows (ph 0-A)
    __half (*u1l)[512]    = (__half(*)[512])smem;           // 10 rows (B-C'), aliases ubar0h
    __half (*u0l)[512]    = (__half(*)[512])(smem + 12288); // 10 rows (y0-1..y0+8)
    __half (*nhl)[512]    = (__half(*)[512])(smem + 22528); // 12 rows (y0-2..y0+9)
    __half (*px1)[512]    = (__half(*)[512])(smem + 34816); // 10 rows (y0-1..y0+8)
    __half (*py1)[512]    = (__half(*)[512])(smem + 45056); // 11 rows (y0-2..y0+8)

    int tid = threadIdx.x;
    int sub = tid >> 6, lane = tid & 63, x0 = lane * 8;
    int y0 = blockIdx.x * RB;
    int b = blockIdx.y;
    size_t plane = (size_t)b * NPIX;
    float sgm = fmaxf(scal[b * 4 + 2], EPSC);
    float inv = 1.0f / sgm;
    const float4 z4 = make_float4(0.f, 0.f, 0.f, 0.f);

    // ---- Phase 0: ubar^t (fp16) + u^t + nh, rows y0-2..y0+9 ----
    for (int i = sub; i < 12; i += 4) {
        int g = y0 - 2 + i;
        if (g >= 0 && g < 512) {
            size_t off = plane + (size_t)g * 512 + x0;
            float4 uraw = *(const float4*)(u + off);
            float uu[8], pp[8], ub[8];
            cvt8h(uraw, uu); ld8h(up + off, pp);
#pragma unroll
            for (int j = 0; j < 8; ++j) ub[j] = 2.f * uu[j] - pp[j];
            *(float4*)&ubar0h[i][x0] = pk8h(ub);
            if (i >= 1 && i <= 10) *(float4*)&u0l[i - 1][x0] = uraw;
            *(float4*)&nhl[i][x0] = *(const float4*)(nh + off);
        } else {
            *(float4*)&ubar0h[i][x0] = z4;
            if (i >= 1 && i <= 10) *(float4*)&u0l[i - 1][x0] = z4;
            *(float4*)&nhl[i][x0] = z4;
        }
    }
    __syncthreads();

    // ---- Phase A: p^{t+1}: py1 rows y0-2..y0+8 (c=0..10), px1 rows y0-1..y0+8 ----
    for (int c = sub; c < 11; c += 4) {
        int g = y0 - 2 + c;
        if (g >= 0 && g < 512) {
            size_t off = plane + (size_t)g * 512 + x0;
            float nhc[8], nhd[8], ubc[8], ubd[8];
            ld8h(&nhl[c][x0], nhc);
            ld8h(&nhl[c + 1][x0], nhd);
            ld8h(&ubar0h[c][x0], ubc);
            ld8h(&ubar0h[c + 1][x0], ubd);
            float nhRr = (lane < 63) ? __half2float(nhl[c][x0 + 8]) : 0.f;
            float ubRr = (lane < 63) ? __half2float(ubar0h[c][x0 + 8]) : 0.f;
            bool rD = (g < 511);
            float py0v[8]; ld8h(pyO + off, py0v);
            float pyv[8];
#pragma unroll
            for (int j = 0; j < 8; ++j) {
                float by = bnd(rD ? (nhd[j] - nhc[j]) : 0.f, inv);
                float dy = rD ? (ubd[j] - ubc[j]) : 0.f;
                pyv[j] = clmp(py0v[j] + SIG * dy, by);
            }
            *(float4*)&py1[c][x0] = pk8h(pyv);
            if (c >= 1) {
                float px0v[8]; ld8h(pxO + off, px0v);
                float pxv[8];
#pragma unroll
                for (int j = 0; j < 8; ++j) {
                    int x = x0 + j;
                    bool xok = (x < 511);
                    float nhr = (j < 7) ? nhc[j + 1] : nhRr;
                    float ubr = (j < 7) ? ubc[j + 1] : ubRr;
                    float bx = bnd(xok ? (nhr - nhc[j]) : 0.f, inv);
                    float dx = xok ? (ubr - ubc[j]) : 0.f;
                    pxv[j] = clmp(px0v[j] + SIG * dx, bx);
                }
                *(float4*)&px1[c - 1][x0] = pk8h(pxv);
            }
        } else {
            *(float4*)&py1[c][x0] = z4;
            if (c >= 1) *(float4*)&px1[c - 1][x0] = z4;
        }
    }
    __syncthreads();

    // ---- Phase B: u^{t+1} rows y0-1..y0+8 (a=0..9) -> u1l (aliases ubar0h) ----
    for (int a = sub; a < 10; a += 4) {
        int g = y0 - 1 + a;
        if (g >= 0 && g < 512) {
            float u0v[8]; ld8h(&u0l[a][x0], u0v);
            float nhc[8];  ld8h(&nhl[a + 1][x0], nhc);
            float px1c[8]; ld8h(&px1[a][x0], px1c);
            float py1c[8]; ld8h(&py1[a + 1][x0], py1c);
            float py1u[8]; ld8h(&py1[a][x0], py1u);
            float pxl = (x0 > 0) ? __half2float(px1[a][x0 - 1]) : 0.f;
            bool gU = (g > 0);
            float uv[8];
#pragma unroll
            for (int j = 0; j < 8; ++j) {
                int x = x0 + j;
                float left = (x > 0) ? ((j > 0) ? px1c[j - 1] : pxl) : 0.f;
                float div = px1c[j] - left + py1c[j] - (gU ? py1u[j] : 0.f);
                uv[j] = (u0v[j] + TAUC * div + TAUC * nhc[j]) * IVT;
            }
            float4 packed = pk8h(uv);
            *(float4*)&u1l[a][x0] = packed;
            if (!last && g >= y0 && g < y0 + RB) {
                size_t off = plane + (size_t)g * 512 + x0;
                *(float4*)(u1g + off) = packed;
            }
        } else {
            *(float4*)&u1l[a][x0] = z4;
        }
    }
    __syncthreads();

    // ---- Phase C': p^{t+2} + u^{t+2}, rows y0..y0+7 (d=sub, sub+4) ----
    for (int d = sub; d < 8; d += 4) {
        int g = y0 + d;
        size_t off = plane + (size_t)g * 512 + x0;
        bool gU = (g > 0), rD = (g < 511);

        float u1m[8], u1c[8], u1d_[8], u0m[8], u0c[8], u0d_[8];
        ld8h(&u1l[d][x0],     u1m);  ld8h(&u0l[d][x0],     u0m);
        ld8h(&u1l[d + 1][x0], u1c);  ld8h(&u0l[d + 1][x0], u0c);
        ld8h(&u1l[d + 2][x0], u1d_); ld8h(&u0l[d + 2][x0], u0d_);
        float nhm[8], nhc[8], nhd[8];
        ld8h(&nhl[d + 1][x0], nhm);
        ld8h(&nhl[d + 2][x0], nhc);
        ld8h(&nhl[d + 3][x0], nhd);
        float ubm[8], ubc[8], ubd[8];
#pragma unroll
        for (int j = 0; j < 8; ++j) {
            ubm[j] = 2.f * u1m[j] - u0m[j];
            ubc[j] = 2.f * u1c[j] - u0c[j];
            ubd[j] = 2.f * u1d_[j] - u0d_[j];
        }

        // py^2 at row g-1 (upper neighbor), bit-identical recompute
        float py1m[8]; ld8h(&py1[d + 1][x0], py1m);
        float py2u[8];
#pragma unroll
        for (int j = 0; j < 8; ++j) {
            float by = bnd(nhc[j] - nhm[j], inv);
            py2u[j] = rth(clmp(py1m[j] + SIG * (ubc[j] - ubm[j]), by));
        }

        // py^2 at row g (own)
        float py1c[8]; ld8h(&py1[d + 2][x0], py1c);
        float pyv[8];
#pragma unroll
        for (int j = 0; j < 8; ++j) {
            float by = bnd(rD ? (nhd[j] - nhc[j]) : 0.f, inv);
            float dy = rD ? (ubd[j] - ubc[j]) : 0.f;
            pyv[j] = rth(clmp(py1c[j] + SIG * dy, by));
        }

        // px^2 at row g
        float px1c[8]; ld8h(&px1[d + 1][x0], px1c);
        float ubRr = (lane < 63) ? (2.f * __half2float(u1l[d + 1][x0 + 8]) - __half2float(u0l[d + 1][x0 + 8])) : 0.f;
        float nhRr = (lane < 63) ? __half2float(nhl[d + 2][x0 + 8]) : 0.f;
        float pxv[8];
#pragma unroll
        for (int j = 0; j < 8; ++j) {
            int x = x0 + j;
            bool xok = (x < 511);
            float nhr = (j < 7) ? nhc[j + 1] : nhRr;
            float ubr = (j < 7) ? ubc[j + 1] : ubRr;
            float bx = bnd(xok ? (nhr - nhc[j]) : 0.f, inv);
            float dx = xok ? (ubr - ubc[j]) : 0.f;
            pxv[j] = rth(clmp(px1c[j] + SIG * dx, bx));
        }
        float pxl = __shfl_up(pxv[7], 1, 64);   // lane-1's last px^2; unused at x0==0

        if (!last) {
            *(float4*)(pxN + off) = pk8h(pxv);
            *(float4*)(pyN + off) = pk8h(pyv);
        }

        float uv[8];
#pragma unroll
        for (int j = 0; j < 8; ++j) {
            int x = x0 + j;
            float left = (x > 0) ? ((j > 0) ? pxv[j - 1] : pxl) : 0.f;
            float div = pxv[j] - left + pyv[j] - (gU ? py2u[j] : 0.f);
            uv[j] = (u1c[j] + TAUC * div + TAUC * nhc[j]) * IVT;
        }
        if (last) {
            float4 o0, o1;
            o0.x = fminf(fmaxf(uv[0], 0.f), 1.f);
            o0.y = fminf(fmaxf(uv[1], 0.f), 1.f);
            o0.z = fminf(fmaxf(uv[2], 0.f), 1.f);
            o0.w = fminf(fmaxf(uv[3], 0.f), 1.f);
            o1.x = fminf(fmaxf(uv[4], 0.f), 1.f);
            o1.y = fminf(fmaxf(uv[5], 0.f), 1.f);
            o1.z = fminf(fmaxf(uv[6], 0.f), 1.f);
            o1.w = fminf(fmaxf(uv[7], 0.f), 1.f);
            *(float4*)(outF + off)     = o0;
            *(float4*)(outF + off + 4) = o1;
        } else {
            *(float4*)(u2g + off) = pk8h(uv);
        }
    }
}

extern "C" void kernel_launch(void* const* d_in, const int* in_sizes, int n_in,
                              void* d_out, int out_size, void* d_ws, size_t ws_size,
                              hipStream_t stream) {
    const float* Iy = (const float*)d_in[0];
    float* out = (float*)d_out;

    dim3 hist_g(HSUB, 16);
    dim3 pd2_g(512 / RB, 16);

    // layout (half units on hb):
    // 0:nhh | NP..5NP: HA..HD | 5NP..9NP: pxA,pyA,pxB,pyB | 9NP: xbh | 10NP..12NP: Hh | 12NP: hist,scal
    __half* hb  = (__half*)d_ws;
    __half* nhh = hb;
    __half* HA  = hb + (size_t)NP;
    __half* HB  = hb + (size_t)2 * NP;
    __half* HC  = hb + (size_t)3 * NP;
    __half* HD  = hb + (size_t)4 * NP;
    __half* pxA = hb + (size_t)5 * NP;
    __half* pyA = hb + (size_t)6 * NP;
    __half* pxB = hb + (size_t)7 * NP;
    __half* pyB = hb + (size_t)8 * NP;
    __half* xbh = hb + (size_t)9 * NP;
    __half* Hh  = hb + (size_t)10 * NP;      // 2 planes (hpass out)
    __half* Vh  = hb + (size_t)1 * NP;       // 2 planes (vpass out; HA..HB region, free now)
    int*    hist = (int*)(hb + (size_t)12 * NP);
    float*  scal = (float*)(hist + 16 * NBINS);

    // 1. separable 31x31 max pool (R and M=max(G,B)) + Dmip combine
    hpass3_k<<<dim3(64, 32), dim3(512), 0, stream>>>(Iy, Hh);
    vpass2h_k<<<dim3(8, 17, 32), dim3(64), 0, stream>>>(Hh, Vh);
    combineh_k<<<NP / 2048, 256, 0, stream>>>(Vh, Iy, xbh);

    // 2. robust normalize -> fp16 N_hat
    hipMemsetAsync(hist, 0, 16 * NBINS * sizeof(int), stream);
    hist2_k<<<hist_g, 1024, 0, stream>>>(xbh, hist);
    quant2_k<<<16, 1024, 0, stream>>>(hist, scal, 0.01f, 0.99f, 0, 1);
    nhat2h_k<<<NP / 2048, 256, 0, stream>>>(xbh, scal, nhh);

    // 3. sigma (median grad mag); zero fp16 p
    hipMemsetAsync(hist, 0, 16 * NBINS * sizeof(int), stream);
    gradhisth_k<<<hist_g, 1024, 0, stream>>>(nhh, hist);
    quant2_k<<<16, 1024, 0, stream>>>(hist, scal, 0.5f, 0.5f, 2, -1);
    hipMemsetAsync(pxA, 0, (size_t)2 * NP * sizeof(__half), stream);

    // 4. 15 fused launches x 2 PD iterations (u_bar = 2u - u_prev)
    const __half* ucur = nhh;
    const __half* uprev = nhh;
    __half* pxs[2] = {pxA, pxB};
    __half* pys[2] = {pyA, pyB};
    for (int k = 0; k < 15; ++k) {
        int cur = k & 1;
        __half* u1o = (k & 1) ? HC : HA;
        __half* u2o = (k & 1) ? HD : HB;
        pdf2_k<<<pd2_g, 256, 0, stream>>>(ucur, uprev,
                                          pxs[cur], pys[cur],
                                          pxs[cur ^ 1], pys[cur ^ 1],
                                          nhh, scal, u1o, u2o, out,
                                          (k == 14) ? 1 : 0);
        uprev = u1o;
        ucur = u2o;
    }
    // k=14 wrote clipped fp32 result directly to out.
}

// Round 13
// 465.060 us; speedup vs baseline: 1.0701x; 1.0701x over previous
//
#include <hip/hip_runtime.h>
#include <hip/hip_bf16.h>
#include <hip/hip_fp16.h>
#include <math.h>

#define NPIX   262144          // 512*512
#define NP     4194304         // 16*512*512
#define NBINS  8192
#define HSUB   16
#define RB     8               // output rows per block in fused PD kernel
#define SIG    0.125f
#define TAUC   0.125f
#define ALPHAC 0.15f
#define MUC    10.0f
#define EPSC   1e-6f
#define NEGINF -3.4e38f
#define IVT    (1.0f / (1.0f + TAUC))

// ---------- helpers ----------
__device__ __forceinline__ void cvt8h(float4 raw, float* d) {
    const __half2* h = (const __half2*)&raw;
#pragma unroll
    for (int j = 0; j < 4; ++j) {
        float2 f = __half22float2(h[j]);
        d[2 * j] = f.x; d[2 * j + 1] = f.y;
    }
}
__device__ __forceinline__ void ld8h(const __half* p, float* d) {
    cvt8h(*(const float4*)p, d);
}
__device__ __forceinline__ float4 pk8h(const float* s) {
    float4 r; __half2* h = (__half2*)&r;
#pragma unroll
    for (int j = 0; j < 4; ++j) h[j] = __floats2half2_rn(s[2 * j], s[2 * j + 1]);
    return r;
}
__device__ __forceinline__ float bnd(float d, float inv) {
    return ALPHAC * (1.f + MUC * __expf(-fabsf(d) * inv));
}
__device__ __forceinline__ float clmp(float v, float b) {
    return fminf(fmaxf(v, -b), b);
}

// ================= POOLING =================

// horizontal 31-max, 3-phase vHGW; fp16 output.
__global__ __launch_bounds__(512) void hpass3_k(const float* __restrict__ Iy,
                                                __half* __restrict__ H) {
    __shared__ float rowbuf[8][512];
    __shared__ float PB[8][512];
    __shared__ float SB[8][512];
    int tid = threadIdx.x;
    int plane = blockIdx.y;
    int y0 = blockIdx.x * 8;

#pragma unroll
    for (int q = 0; q < 2; ++q) {
        int idx = q * 512 + tid;
        int r = idx >> 7;
        int x4 = (idx & 127) << 2;
        float4 v;
        if (plane < 16) {
            v = *(const float4*)(Iy + (size_t)(plane * 3) * NPIX + (size_t)(y0 + r) * 512 + x4);
        } else {
            int b = plane - 16;
            float4 g = *(const float4*)(Iy + ((size_t)(b * 3) + 1) * NPIX + (size_t)(y0 + r) * 512 + x4);
            float4 bb = *(const float4*)(Iy + ((size_t)(b * 3) + 2) * NPIX + (size_t)(y0 + r) * 512 + x4);
            v = make_float4(fmaxf(g.x, bb.x), fmaxf(g.y, bb.y), fmaxf(g.z, bb.z), fmaxf(g.w, bb.w));
        }
        *(float4*)(&rowbuf[r][x4]) = v;
    }
    __syncthreads();

    if (tid < 272) {
        int type = tid / 136;
        int rem = tid % 136;
        int r = rem / 17;
        int seg = rem % 17;
        int s0 = seg * 31;
        if (type == 0) {
            float run = rowbuf[r][s0];
            PB[r][s0] = run;
            for (int j = 1; j < 31; ++j) {
                int idx = s0 + j;
                if (idx < 512) { run = fmaxf(run, rowbuf[r][idx]); PB[r][idx] = run; }
            }
        } else {
            int s1 = min(s0 + 30, 511);
            float run = rowbuf[r][s1];
            SB[r][s1] = run;
            for (int j = s1 - 1; j >= s0; --j) { run = fmaxf(run, rowbuf[r][j]); SB[r][j] = run; }
        }
    }
    __syncthreads();

    int x = tid, a = x - 15, bc = x + 15;
#pragma unroll
    for (int r = 0; r < 8; ++r) {
        float o;
        if (a < 0)        o = PB[r][bc];
        else if (bc > 511) o = fmaxf(SB[r][a], PB[r][511]);
        else              o = fmaxf(SB[r][a], PB[r][bc]);
        H[(size_t)plane * NPIX + (size_t)(y0 + r) * 512 + x] = __float2half_rn(o);
    }
}

// vertical 31-max, one plane x one segment per block. grid (8, 17, 32), block 64.
__global__ __launch_bounds__(64) void vpass2h_k(const __half* __restrict__ H,
                                                __half* __restrict__ V) {
    int x = blockIdx.x * 64 + threadIdx.x;
    int s = blockIdx.y;                 // 0..16
    const __half* in = H + (size_t)blockIdx.z * NPIX;
    __half*      out = V + (size_t)blockIdx.z * NPIX;
    int s0 = s * 31;

    float Sprev[31];
    if (s > 0) {
        int p0 = s0 - 31;
        float v[31];
#pragma unroll
        for (int j = 0; j < 31; ++j) v[j] = __half2float(in[(size_t)(p0 + j) * 512 + x]);
        float acc = NEGINF;
#pragma unroll
        for (int j = 30; j >= 0; --j) { acc = fmaxf(acc, v[j]); Sprev[j] = acc; }
    } else {
#pragma unroll
        for (int j = 0; j < 31; ++j) Sprev[j] = NEGINF;
    }

    float P = NEGINF;
#pragma unroll
    for (int r = 0; r < 31; ++r) {
        float vv = (s0 + r < 512) ? __half2float(in[(size_t)(s0 + r) * 512 + x]) : NEGINF;
        P = fmaxf(P, vv);
        int i = s0 + r - 15;
        if (i >= 0 && i <= 511) {
            int a = s0 + r - 30;
            float o;
            if (a < 0)       o = P;
            else if (r == 30) o = P;
            else              o = fmaxf(Sprev[r + 1], P);
            out[(size_t)i * 512 + x] = __float2half_rn(o);
        }
    }
}

// combine: xb = |vR - vM| + R, 8 px/thread
__global__ __launch_bounds__(256) void combineh_k(const __half* __restrict__ V,
                                                  const float* __restrict__ Iy,
                                                  __half* __restrict__ xb) {
    size_t i = ((size_t)blockIdx.x * 256 + threadIdx.x) * 8;
    int b = (int)(i >> 18);
    size_t off = i & (NPIX - 1);
    float vr[8], vm[8];
    ld8h(V + (size_t)b * NPIX + off, vr);
    ld8h(V + (size_t)(16 + b) * NPIX + off, vm);
    const float* R = Iy + (size_t)(b * 3) * NPIX + off;
    float4 r0 = *(const float4*)R;
    float4 r1 = *(const float4*)(R + 4);
    float rr[8] = {r0.x, r0.y, r0.z, r0.w, r1.x, r1.y, r1.z, r1.w};
    float a[8];
#pragma unroll
    for (int j = 0; j < 8; ++j) a[j] = fabsf(vr[j] - vm[j]) + rr[j];
    *(float4*)(xb + i) = pk8h(a);
}

// ================= HISTOGRAM / QUANTILE =================

__global__ __launch_bounds__(1024) void hist2_k(const __half* __restrict__ v,
                                                int* __restrict__ hist) {
    __shared__ int lh[NBINS];
    int s = blockIdx.x, b = blockIdx.y, tid = threadIdx.x;
    for (int i = tid; i < NBINS; i += 1024) lh[i] = 0;
    __syncthreads();
    const __half* p = v + (size_t)b * NPIX + (size_t)s * (NPIX / HSUB);
    for (int i = tid; i < NPIX / HSUB; i += 1024) {
        int bin = (int)(__half2float(p[i]) * (NBINS * 0.5f));
        bin = min(max(bin, 0), NBINS - 1);
        atomicAdd(&lh[bin], 1);
    }
    __syncthreads();
    for (int i = tid; i < NBINS; i += 1024) {
        int c = lh[i];
        if (c) atomicAdd(&hist[b * NBINS + i], c);
    }
}

__global__ __launch_bounds__(1024) void gradhisth_k(const __half* __restrict__ nh,
                                                    int* __restrict__ hist) {
    __shared__ int lh[NBINS];
    int s = blockIdx.x, b = blockIdx.y, tid = threadIdx.x;
    for (int i = tid; i < NBINS; i += 1024) lh[i] = 0;
    __syncthreads();
    const __half* p = nh + (size_t)b * NPIX;
    int base = s * (NPIX / HSUB);
    for (int ii = tid; ii < NPIX / HSUB; ii += 1024) {
        int i = base + ii;
        float c = __half2float(p[i]);
        int x = i & 511, y = i >> 9;
        float dx = (x < 511) ? __half2float(p[i + 1])   - c : 0.f;
        float dy = (y < 511) ? __half2float(p[i + 512]) - c : 0.f;
        float gm = sqrtf(dx * dx + dy * dy + EPSC);
        int bin = (int)(gm * (NBINS * 0.5f));
        bin = min(max(bin, 0), NBINS - 1);
        atomicAdd(&lh[bin], 1);
    }
    __syncthreads();
    for (int i = tid; i < NBINS; i += 1024) {
        int c = lh[i];
        if (c) atomicAdd(&hist[b * NBINS + i], c);
    }
}

__global__ __launch_bounds__(1024) void quant2_k(const int* __restrict__ hist,
                                                 float* __restrict__ scal,
                                                 float q0, float q1, int s0, int s1) {
    __shared__ int csum[1025];
    __shared__ int wsum[16];
    int b = blockIdx.x, tid = threadIdx.x;
    const int* h = hist + b * NBINS;
    int s = 0;
#pragma unroll
    for (int j = 0; j < NBINS / 1024; ++j) s += h[tid * (NBINS / 1024) + j];

    int lane = tid & 63, wave = tid >> 6;
    int v = s;
#pragma unroll
    for (int off = 1; off < 64; off <<= 1) {
        int n = __shfl_up(v, off, 64);
        if (lane >= off) v += n;
    }
    if (lane == 63) wsum[wave] = v;
    __syncthreads();
    if (wave == 0 && lane < 16) {
        int w = wsum[lane];
#pragma unroll
        for (int off = 1; off < 16; off <<= 1) {
            int n = __shfl_up(w, off, 64);
            if (lane >= off) w += n;
        }
        wsum[lane] = w;
    }
    __syncthreads();
    int incl = v + (wave > 0 ? wsum[wave - 1] : 0);
    csum[tid + 1] = incl;
    if (tid == 0) csum[0] = 0;
    __syncthreads();

#pragma unroll
    for (int pass = 0; pass < 2; ++pass) {
        int slot = pass ? s1 : s0;
        if (slot < 0) continue;
        float q = pass ? q1 : q0;
        float t = q * (float)(NPIX - 1);
        if ((float)csum[tid] <= t && (float)csum[tid + 1] > t) {
            const int per = NBINS / 1024;
            int cb = csum[tid];
            int bin = tid * per;
            int hv = 1;
            for (int j = 0; j < per; ++j) {
                hv = h[tid * per + j];
                if ((float)(cb + hv) > t) { bin = tid * per + j; break; }
                cb += hv;
            }
            float k = t - (float)cb;
            scal[b * 4 + slot] = ((float)bin + (k + 0.5f) / (float)hv) * (2.0f / NBINS);
        }
    }
}

// ---------------- N_hat (fp16) from xb (fp16), 8 px/thread ----------------
__global__ __launch_bounds__(256) void nhat2h_k(const __half* __restrict__ xb,
                                                const float* __restrict__ scal,
                                                __half* __restrict__ nhh) {
    size_t i = ((size_t)blockIdx.x * 256 + threadIdx.x) * 8;
    int b = (int)(i >> 18);
    float lo = scal[b * 4 + 0], hi = scal[b * 4 + 1];
    float inv = 1.0f / (hi - lo + EPSC);
    float v[8]; ld8h(xb + i, v);
    float a[8];
#pragma unroll
    for (int j = 0; j < 8; ++j)
        a[j] = fminf(fmaxf((v[j] - lo) * inv, 0.f), 1.f);
    *(float4*)(nhh + i) = pk8h(a);
}

// ================= FUSED 2-ITERATION PD KERNEL (75 KB LDS, global-free B-D) ==
// Round-11 proven structure + XCD-aware block swizzle (1D grid, bijective).
__global__ __launch_bounds__(256) void pdf2_k(const __half* __restrict__ u,
                                              const __half* __restrict__ up,
                                              const __half* __restrict__ pxO,
                                              const __half* __restrict__ pyO,
                                              __half* __restrict__ pxN,
                                              __half* __restrict__ pyN,
                                              const __half* __restrict__ nh,
                                              const float* __restrict__ scal,
                                              __half* __restrict__ u1g,
                                              __half* __restrict__ u2g,
                                              float* __restrict__ outF,
                                              int last) {
    __shared__ __align__(16) char smem[76800];              // 75 KB
    __half (*ubar0h)[512] = (__half(*)[512])smem;           // 12 rows (ph 0-A)
    __half (*py2l)[512]   = (__half(*)[512])smem;           // 9 rows (ph C+), aliases ubar0h
    __half (*u0l)[512]    = (__half(*)[512])(smem + 12288); // 12 rows (y0-2..y0+9)
    __half (*nhl)[512]    = (__half(*)[512])(smem + 24576); // 12 rows
    __half (*px1)[512]    = (__half(*)[512])(smem + 36864); // 10 rows (y0-1..y0+8)
    __half (*py1)[512]    = (__half(*)[512])(smem + 47104); // 11 rows (y0-2..y0+8)
    __half (*u1l)[512]    = (__half(*)[512])(smem + 58368); // 10 rows (y0-1..y0+8)
    __half (*px2l)[512]   = (__half(*)[512])(smem + 68608); // 8 rows  (y0..y0+7)

    int tid = threadIdx.x;
    int sub = tid >> 6, lane = tid & 63, x0 = lane * 8;
    // XCD swizzle: gid -> (batch, y-tile) so each XCD (gid%8) owns 2 whole
    // batches contiguously; halo neighbors + inter-launch reuse stay in one L2.
    int gid = blockIdx.x;                       // 0..1023
    int swz = (gid & 7) * 128 + (gid >> 3);     // bijective on [0,1024)
    int b  = swz >> 6;
    int y0 = (swz & 63) * RB;
    size_t plane = (size_t)b * NPIX;
    float sgm = fmaxf(scal[b * 4 + 2], EPSC);
    float inv = 1.0f / sgm;
    const float4 z4 = make_float4(0.f, 0.f, 0.f, 0.f);

    // ---- Phase 0: u^t (raw) + ubar^t (fp16) + nh, rows y0-2..y0+9 ----
    for (int i = sub; i < 12; i += 4) {
        int g = y0 - 2 + i;
        if (g >= 0 && g < 512) {
            size_t off = plane + (size_t)g * 512 + x0;
            float4 uraw = *(const float4*)(u + off);
            float uu[8], pp[8], ub[8];
            cvt8h(uraw, uu); ld8h(up + off, pp);
#pragma unroll
            for (int j = 0; j < 8; ++j) ub[j] = 2.f * uu[j] - pp[j];
            *(float4*)&ubar0h[i][x0] = pk8h(ub);
            *(float4*)&u0l[i][x0] = uraw;
            *(float4*)&nhl[i][x0] = *(const float4*)(nh + off);
        } else {
            *(float4*)&ubar0h[i][x0] = z4;
            *(float4*)&u0l[i][x0] = z4;
            *(float4*)&nhl[i][x0] = z4;
        }
    }
    __syncthreads();

    // ---- Phase A: p^{t+1}: py1 rows y0-2..y0+8 (c=0..10), px1 rows y0-1..y0+8 ----
    for (int c = sub; c < 11; c += 4) {
        int g = y0 - 2 + c;
        if (g >= 0 && g < 512) {
            size_t off = plane + (size_t)g * 512 + x0;
            float nhc[8], nhd[8], ubc[8], ubd[8];
            ld8h(&nhl[c][x0], nhc);
            ld8h(&nhl[c + 1][x0], nhd);
            ld8h(&ubar0h[c][x0], ubc);
            ld8h(&ubar0h[c + 1][x0], ubd);
            float nhRr = (lane < 63) ? __half2float(nhl[c][x0 + 8]) : 0.f;
            float ubRr = (lane < 63) ? __half2float(ubar0h[c][x0 + 8]) : 0.f;
            bool rD = (g < 511);
            float py0v[8]; ld8h(pyO + off, py0v);
            float pyv[8];
#pragma unroll
            for (int j = 0; j < 8; ++j) {
                float by = bnd(rD ? (nhd[j] - nhc[j]) : 0.f, inv);
                float dy = rD ? (ubd[j] - ubc[j]) : 0.f;
                pyv[j] = clmp(py0v[j] + SIG * dy, by);
            }
            *(float4*)&py1[c][x0] = pk8h(pyv);
            if (c >= 1) {
                float px0v[8]; ld8h(pxO + off, px0v);
                float pxv[8];
#pragma unroll
                for (int j = 0; j < 8; ++j) {
                    int x = x0 + j;
                    bool xok = (x < 511);
                    float nhr = (j < 7) ? nhc[j + 1] : nhRr;
                    float ubr = (j < 7) ? ubc[j + 1] : ubRr;
                    float bx = bnd(xok ? (nhr - nhc[j]) : 0.f, inv);
                    float dx = xok ? (ubr - ubc[j]) : 0.f;
                    pxv[j] = clmp(px0v[j] + SIG * dx, bx);
                }
                *(float4*)&px1[c - 1][x0] = pk8h(pxv);
            }
        } else {
            *(float4*)&py1[c][x0] = z4;
            if (c >= 1) *(float4*)&px1[c - 1][x0] = z4;
        }
    }
    __syncthreads();

    // ---- Phase B: u^{t+1} rows y0-1..y0+8 (a=0..9) -> u1l; interior -> u1g ----
    for (int a = sub; a < 10; a += 4) {
        int g = y0 - 1 + a;
        if (g >= 0 && g < 512) {
            float u0v[8]; ld8h(&u0l[a + 1][x0], u0v);
            float nhc[8];  ld8h(&nhl[a + 1][x0], nhc);
            float px1c[8]; ld8h(&px1[a][x0], px1c);
            float py1c[8]; ld8h(&py1[a + 1][x0], py1c);
            float py1u[8]; ld8h(&py1[a][x0], py1u);
            float pxl = (x0 > 0) ? __half2float(px1[a][x0 - 1]) : 0.f;
            bool gU = (g > 0);
            float uv[8];
#pragma unroll
            for (int j = 0; j < 8; ++j) {
                int x = x0 + j;
                float left = (x > 0) ? ((j > 0) ? px1c[j - 1] : pxl) : 0.f;
                float div = px1c[j] - left + py1c[j] - (gU ? py1u[j] : 0.f);
                uv[j] = (u0v[j] + TAUC * div + TAUC * nhc[j]) * IVT;
            }
            float4 packed = pk8h(uv);
            *(float4*)&u1l[a][x0] = packed;
            if (!last && g >= y0 && g < y0 + RB) {
                size_t off = plane + (size_t)g * 512 + x0;
                *(float4*)(u1g + off) = packed;
            }
        } else {
            *(float4*)&u1l[a][x0] = z4;
        }
    }
    __syncthreads();

    // ---- Phase C: p^{t+2}: py2 rows y0-1..y0+7 (e=0..8), px2 rows y0..y0+7 ----
    // (py2l aliases ubar0h, dead since the barrier after phase A)
    for (int e = sub; e < 9; e += 4) {
        int g = y0 - 1 + e;
        if (g >= 0) {                      // g <= 511 always here
            size_t off = plane + (size_t)g * 512 + x0;
            float u1c[8], u0c[8], u1d[8], u0d[8];
            ld8h(&u1l[e][x0], u1c);     ld8h(&u0l[e + 1][x0], u0c);
            ld8h(&u1l[e + 1][x0], u1d); ld8h(&u0l[e + 2][x0], u0d);
            float nhc[8], nhd[8];
            ld8h(&nhl[e + 1][x0], nhc); ld8h(&nhl[e + 2][x0], nhd);
            float ubc[8], ubd[8];
#pragma unroll
            for (int j = 0; j < 8; ++j) {
                ubc[j] = 2.f * u1c[j] - u0c[j];
                ubd[j] = 2.f * u1d[j] - u0d[j];
            }
            float ubRr = (lane < 63) ? (2.f * __half2float(u1l[e][x0 + 8]) - __half2float(u0l[e + 1][x0 + 8])) : 0.f;
            float nhRr = (lane < 63) ? __half2float(nhl[e + 1][x0 + 8]) : 0.f;
            bool rD = (g < 511);
            float py1c[8]; ld8h(&py1[e + 1][x0], py1c);
            float pyv[8];
#pragma unroll
            for (int j = 0; j < 8; ++j) {
                float by = bnd(rD ? (nhd[j] - nhc[j]) : 0.f, inv);
                float dy = rD ? (ubd[j] - ubc[j]) : 0.f;
                pyv[j] = clmp(py1c[j] + SIG * dy, by);
            }
            float4 pyp = pk8h(pyv);
            *(float4*)&py2l[e][x0] = pyp;
            if (!last && g >= y0) *(float4*)(pyN + off) = pyp;
            if (e >= 1) {
                float px1c[8]; ld8h(&px1[e][x0], px1c);
                float pxv[8];
#pragma unroll
                for (int j = 0; j < 8; ++j) {
                    int x = x0 + j;
                    bool xok = (x < 511);
                    float nhr = (j < 7) ? nhc[j + 1] : nhRr;
                    float ubr = (j < 7) ? ubc[j + 1] : ubRr;
                    float bx = bnd(xok ? (nhr - nhc[j]) : 0.f, inv);
                    float dx = xok ? (ubr - ubc[j]) : 0.f;
                    pxv[j] = clmp(px1c[j] + SIG * dx, bx);
                }
                float4 pxp = pk8h(pxv);
                *(float4*)&px2l[e - 1][x0] = pxp;
                if (!last) *(float4*)(pxN + off) = pxp;
            }
        } else {
            *(float4*)&py2l[e][x0] = z4;
        }
    }
    __syncthreads();

    // ---- Phase D: u^{t+2} rows y0..y0+7 ----
    for (int d = sub; d < 8; d += 4) {
        int g = y0 + d;
        size_t off = plane + (size_t)g * 512 + x0;
        float px2c[8]; ld8h(&px2l[d][x0], px2c);
        float py2c[8]; ld8h(&py2l[d + 1][x0], py2c);
        float py2u[8]; ld8h(&py2l[d][x0], py2u);
        float pxl = (x0 > 0) ? __half2float(px2l[d][x0 - 1]) : 0.f;
        float u1c[8]; ld8h(&u1l[d + 1][x0], u1c);
        float nhc[8]; ld8h(&nhl[d + 2][x0], nhc);
        bool gU = (g > 0);
        float uv[8];
#pragma unroll
        for (int j = 0; j < 8; ++j) {
            int x = x0 + j;
            float left = (x > 0) ? ((j > 0) ? px2c[j - 1] : pxl) : 0.f;
            float div = px2c[j] - left + py2c[j] - (gU ? py2u[j] : 0.f);
            uv[j] = (u1c[j] + TAUC * div + TAUC * nhc[j]) * IVT;
        }
        if (last) {
            float4 o0, o1;
            o0.x = fminf(fmaxf(uv[0], 0.f), 1.f);
            o0.y = fminf(fmaxf(uv[1], 0.f), 1.f);
            o0.z = fminf(fmaxf(uv[2], 0.f), 1.f);
            o0.w = fminf(fmaxf(uv[3], 0.f), 1.f);
            o1.x = fminf(fmaxf(uv[4], 0.f), 1.f);
            o1.y = fminf(fmaxf(uv[5], 0.f), 1.f);
            o1.z = fminf(fmaxf(uv[6], 0.f), 1.f);
            o1.w = fminf(fmaxf(uv[7], 0.f), 1.f);
            *(float4*)(outF + off)     = o0;
            *(float4*)(outF + off + 4) = o1;
        } else {
            *(float4*)(u2g + off) = pk8h(uv);
        }
    }
}

extern "C" void kernel_launch(void* const* d_in, const int* in_sizes, int n_in,
                              void* d_out, int out_size, void* d_ws, size_t ws_size,
                              hipStream_t stream) {
    const float* Iy = (const float*)d_in[0];
    float* out = (float*)d_out;

    dim3 hist_g(HSUB, 16);

    // layout (half units on hb):
    // 0:nhh | NP..5NP: HA..HD | 5NP..9NP: pxA,pyA,pxB,pyB | 9NP: xbh | 10NP..12NP: Hh | 12NP: hist,scal
    __half* hb  = (__half*)d_ws;
    __half* nhh = hb;
    __half* HA  = hb + (size_t)NP;
    __half* HB  = hb + (size_t)2 * NP;
    __half* HC  = hb + (size_t)3 * NP;
    __half* HD  = hb + (size_t)4 * NP;
    __half* pxA = hb + (size_t)5 * NP;
    __half* pyA = hb + (size_t)6 * NP;
    __half* pxB = hb + (size_t)7 * NP;
    __half* pyB = hb + (size_t)8 * NP;
    __half* xbh = hb + (size_t)9 * NP;
    __half* Hh  = hb + (size_t)10 * NP;      // 2 planes (hpass out)
    __half* Vh  = hb + (size_t)1 * NP;       // 2 planes (vpass out; HA..HB region, free now)
    int*    hist = (int*)(hb + (size_t)12 * NP);
    float*  scal = (float*)(hist + 16 * NBINS);

    // 1. separable 31x31 max pool (R and M=max(G,B)) + Dmip combine
    hpass3_k<<<dim3(64, 32), dim3(512), 0, stream>>>(Iy, Hh);
    vpass2h_k<<<dim3(8, 17, 32), dim3(64), 0, stream>>>(Hh, Vh);
    combineh_k<<<NP / 2048, 256, 0, stream>>>(Vh, Iy, xbh);

    // 2. robust normalize -> fp16 N_hat
    hipMemsetAsync(hist, 0, 16 * NBINS * sizeof(int), stream);
    hist2_k<<<hist_g, 1024, 0, stream>>>(xbh, hist);
    quant2_k<<<16, 1024, 0, stream>>>(hist, scal, 0.01f, 0.99f, 0, 1);
    nhat2h_k<<<NP / 2048, 256, 0, stream>>>(xbh, scal, nhh);

    // 3. sigma (median grad mag); zero fp16 p
    hipMemsetAsync(hist, 0, 16 * NBINS * sizeof(int), stream);
    gradhisth_k<<<hist_g, 1024, 0, stream>>>(nhh, hist);
    quant2_k<<<16, 1024, 0, stream>>>(hist, scal, 0.5f, 0.5f, 2, -1);
    hipMemsetAsync(pxA, 0, (size_t)2 * NP * sizeof(__half), stream);

    // 4. 15 fused launches x 2 PD iterations (u_bar = 2u - u_prev)
    const __half* ucur = nhh;
    const __half* uprev = nhh;
    __half* pxs[2] = {pxA, pxB};
    __half* pys[2] = {pyA, pyB};
    for (int k = 0; k < 15; ++k) {
        int cur = k & 1;
        __half* u1o = (k & 1) ? HC : HA;
        __half* u2o = (k & 1) ? HD : HB;
        pdf2_k<<<dim3(1024), 256, 0, stream>>>(ucur, uprev,
                                               pxs[cur], pys[cur],
                                               pxs[cur ^ 1], pys[cur ^ 1],
                                               nhh, scal, u1o, u2o, out,
                                               (k == 14) ? 1 : 0);
        uprev = u1o;
        ucur = u2o;
    }
    // k=14 wrote clipped fp32 result directly to out.
}

// Round 14
// 430.787 us; speedup vs baseline: 1.1552x; 1.0796x over previous
//
#include <hip/hip_runtime.h>
#include <hip/hip_bf16.h>
#include <hip/hip_fp16.h>
#include <math.h>

#define NPIX   262144          // 512*512
#define NP     4194304         // 16*512*512
#define NBINS  8192
#define HSUB   16
#define RB     8               // output rows per block in fused PD kernel
#define SIG    0.125f
#define TAUC   0.125f
#define ALPHAC 0.15f
#define MUC    10.0f
#define EPSC   1e-6f
#define NEGINF -3.4e38f
#define IVT    (1.0f / (1.0f + TAUC))

// ---------- helpers ----------
__device__ __forceinline__ void cvt8h(float4 raw, float* d) {
    const __half2* h = (const __half2*)&raw;
#pragma unroll
    for (int j = 0; j < 4; ++j) {
        float2 f = __half22float2(h[j]);
        d[2 * j] = f.x; d[2 * j + 1] = f.y;
    }
}
__device__ __forceinline__ void ld8h(const __half* p, float* d) {
    cvt8h(*(const float4*)p, d);
}
__device__ __forceinline__ float4 pk8h(const float* s) {
    float4 r; __half2* h = (__half2*)&r;
#pragma unroll
    for (int j = 0; j < 4; ++j) h[j] = __floats2half2_rn(s[2 * j], s[2 * j + 1]);
    return r;
}
__device__ __forceinline__ float bnd(float d, float inv) {
    return ALPHAC * (1.f + MUC * __expf(-fabsf(d) * inv));
}
__device__ __forceinline__ float clmp(float v, float b) {
    return fminf(fmaxf(v, -b), b);
}

// ================= POOLING =================

// horizontal 31-max, 3-phase vHGW; fp16 output.
__global__ __launch_bounds__(512) void hpass3_k(const float* __restrict__ Iy,
                                                __half* __restrict__ H) {
    __shared__ float rowbuf[8][512];
    __shared__ float PB[8][512];
    __shared__ float SB[8][512];
    int tid = threadIdx.x;
    int plane = blockIdx.y;
    int y0 = blockIdx.x * 8;

#pragma unroll
    for (int q = 0; q < 2; ++q) {
        int idx = q * 512 + tid;
        int r = idx >> 7;
        int x4 = (idx & 127) << 2;
        float4 v;
        if (plane < 16) {
            v = *(const float4*)(Iy + (size_t)(plane * 3) * NPIX + (size_t)(y0 + r) * 512 + x4);
        } else {
            int b = plane - 16;
            float4 g = *(const float4*)(Iy + ((size_t)(b * 3) + 1) * NPIX + (size_t)(y0 + r) * 512 + x4);
            float4 bb = *(const float4*)(Iy + ((size_t)(b * 3) + 2) * NPIX + (size_t)(y0 + r) * 512 + x4);
            v = make_float4(fmaxf(g.x, bb.x), fmaxf(g.y, bb.y), fmaxf(g.z, bb.z), fmaxf(g.w, bb.w));
        }
        *(float4*)(&rowbuf[r][x4]) = v;
    }
    __syncthreads();

    if (tid < 272) {
        int type = tid / 136;
        int rem = tid % 136;
        int r = rem / 17;
        int seg = rem % 17;
        int s0 = seg * 31;
        if (type == 0) {
            float run = rowbuf[r][s0];
            PB[r][s0] = run;
            for (int j = 1; j < 31; ++j) {
                int idx = s0 + j;
                if (idx < 512) { run = fmaxf(run, rowbuf[r][idx]); PB[r][idx] = run; }
            }
        } else {
            int s1 = min(s0 + 30, 511);
            float run = rowbuf[r][s1];
            SB[r][s1] = run;
            for (int j = s1 - 1; j >= s0; --j) { run = fmaxf(run, rowbuf[r][j]); SB[r][j] = run; }
        }
    }
    __syncthreads();

    int x = tid, a = x - 15, bc = x + 15;
#pragma unroll
    for (int r = 0; r < 8; ++r) {
        float o;
        if (a < 0)        o = PB[r][bc];
        else if (bc > 511) o = fmaxf(SB[r][a], PB[r][511]);
        else              o = fmaxf(SB[r][a], PB[r][bc]);
        H[(size_t)plane * NPIX + (size_t)(y0 + r) * 512 + x] = __float2half_rn(o);
    }
}

// vertical 31-max, one plane x one segment per block. grid (8, 17, 32), block 64.
__global__ __launch_bounds__(64) void vpass2h_k(const __half* __restrict__ H,
                                                __half* __restrict__ V) {
    int x = blockIdx.x * 64 + threadIdx.x;
    int s = blockIdx.y;                 // 0..16
    const __half* in = H + (size_t)blockIdx.z * NPIX;
    __half*      out = V + (size_t)blockIdx.z * NPIX;
    int s0 = s * 31;

    float Sprev[31];
    if (s > 0) {
        int p0 = s0 - 31;
        float v[31];
#pragma unroll
        for (int j = 0; j < 31; ++j) v[j] = __half2float(in[(size_t)(p0 + j) * 512 + x]);
        float acc = NEGINF;
#pragma unroll
        for (int j = 30; j >= 0; --j) { acc = fmaxf(acc, v[j]); Sprev[j] = acc; }
    } else {
#pragma unroll
        for (int j = 0; j < 31; ++j) Sprev[j] = NEGINF;
    }

    float P = NEGINF;
#pragma unroll
    for (int r = 0; r < 31; ++r) {
        float vv = (s0 + r < 512) ? __half2float(in[(size_t)(s0 + r) * 512 + x]) : NEGINF;
        P = fmaxf(P, vv);
        int i = s0 + r - 15;
        if (i >= 0 && i <= 511) {
            int a = s0 + r - 30;
            float o;
            if (a < 0)       o = P;
            else if (r == 30) o = P;
            else              o = fmaxf(Sprev[r + 1], P);
            out[(size_t)i * 512 + x] = __float2half_rn(o);
        }
    }
}

// combine: xb = |vR - vM| + R, 8 px/thread
__global__ __launch_bounds__(256) void combineh_k(const __half* __restrict__ V,
                                                  const float* __restrict__ Iy,
                                                  __half* __restrict__ xb) {
    size_t i = ((size_t)blockIdx.x * 256 + threadIdx.x) * 8;
    int b = (int)(i >> 18);
    size_t off = i & (NPIX - 1);
    float vr[8], vm[8];
    ld8h(V + (size_t)b * NPIX + off, vr);
    ld8h(V + (size_t)(16 + b) * NPIX + off, vm);
    const float* R = Iy + (size_t)(b * 3) * NPIX + off;
    float4 r0 = *(const float4*)R;
    float4 r1 = *(const float4*)(R + 4);
    float rr[8] = {r0.x, r0.y, r0.z, r0.w, r1.x, r1.y, r1.z, r1.w};
    float a[8];
#pragma unroll
    for (int j = 0; j < 8; ++j) a[j] = fabsf(vr[j] - vm[j]) + rr[j];
    *(float4*)(xb + i) = pk8h(a);
}

// ================= HISTOGRAM / QUANTILE =================

__global__ __launch_bounds__(1024) void hist2_k(const __half* __restrict__ v,
                                                int* __restrict__ hist) {
    __shared__ int lh[NBINS];
    int s = blockIdx.x, b = blockIdx.y, tid = threadIdx.x;
    for (int i = tid; i < NBINS; i += 1024) lh[i] = 0;
    __syncthreads();
    const __half* p = v + (size_t)b * NPIX + (size_t)s * (NPIX / HSUB);
    for (int i = tid; i < NPIX / HSUB; i += 1024) {
        int bin = (int)(__half2float(p[i]) * (NBINS * 0.5f));
        bin = min(max(bin, 0), NBINS - 1);
        atomicAdd(&lh[bin], 1);
    }
    __syncthreads();
    for (int i = tid; i < NBINS; i += 1024) {
        int c = lh[i];
        if (c) atomicAdd(&hist[b * NBINS + i], c);
    }
}

__global__ __launch_bounds__(1024) void gradhisth_k(const __half* __restrict__ nh,
                                                    int* __restrict__ hist) {
    __shared__ int lh[NBINS];
    int s = blockIdx.x, b = blockIdx.y, tid = threadIdx.x;
    for (int i = tid; i < NBINS; i += 1024) lh[i] = 0;
    __syncthreads();
    const __half* p = nh + (size_t)b * NPIX;
    int base = s * (NPIX / HSUB);
    for (int ii = tid; ii < NPIX / HSUB; ii += 1024) {
        int i = base + ii;
        float c = __half2float(p[i]);
        int x = i & 511, y = i >> 9;
        float dx = (x < 511) ? __half2float(p[i + 1])   - c : 0.f;
        float dy = (y < 511) ? __half2float(p[i + 512]) - c : 0.f;
        float gm = sqrtf(dx * dx + dy * dy + EPSC);
        int bin = (int)(gm * (NBINS * 0.5f));
        bin = min(max(bin, 0), NBINS - 1);
        atomicAdd(&lh[bin], 1);
    }
    __syncthreads();
    for (int i = tid; i < NBINS; i += 1024) {
        int c = lh[i];
        if (c) atomicAdd(&hist[b * NBINS + i], c);
    }
}

__global__ __launch_bounds__(1024) void quant2_k(const int* __restrict__ hist,
                                                 float* __restrict__ scal,
                                                 float q0, float q1, int s0, int s1) {
    __shared__ int csum[1025];
    __shared__ int wsum[16];
    int b = blockIdx.x, tid = threadIdx.x;
    const int* h = hist + b * NBINS;
    int s = 0;
#pragma unroll
    for (int j = 0; j < NBINS / 1024; ++j) s += h[tid * (NBINS / 1024) + j];

    int lane = tid & 63, wave = tid >> 6;
    int v = s;
#pragma unroll
    for (int off = 1; off < 64; off <<= 1) {
        int n = __shfl_up(v, off, 64);
        if (lane >= off) v += n;
    }
    if (lane == 63) wsum[wave] = v;
    __syncthreads();
    if (wave == 0 && lane < 16) {
        int w = wsum[lane];
#pragma unroll
        for (int off = 1; off < 16; off <<= 1) {
            int n = __shfl_up(w, off, 64);
            if (lane >= off) w += n;
        }
        wsum[lane] = w;
    }
    __syncthreads();
    int incl = v + (wave > 0 ? wsum[wave - 1] : 0);
    csum[tid + 1] = incl;
    if (tid == 0) csum[0] = 0;
    __syncthreads();

#pragma unroll
    for (int pass = 0; pass < 2; ++pass) {
        int slot = pass ? s1 : s0;
        if (slot < 0) continue;
        float q = pass ? q1 : q0;
        float t = q * (float)(NPIX - 1);
        if ((float)csum[tid] <= t && (float)csum[tid + 1] > t) {
            const int per = NBINS / 1024;
            int cb = csum[tid];
            int bin = tid * per;
            int hv = 1;
            for (int j = 0; j < per; ++j) {
                hv = h[tid * per + j];
                if ((float)(cb + hv) > t) { bin = tid * per + j; break; }
                cb += hv;
            }
            float k = t - (float)cb;
            scal[b * 4 + slot] = ((float)bin + (k + 0.5f) / (float)hv) * (2.0f / NBINS);
        }
    }
}

// ---------------- N_hat (fp16) from xb (fp16), 8 px/thread ----------------
__global__ __launch_bounds__(256) void nhat2h_k(const __half* __restrict__ xb,
                                                const float* __restrict__ scal,
                                                __half* __restrict__ nhh) {
    size_t i = ((size_t)blockIdx.x * 256 + threadIdx.x) * 8;
    int b = (int)(i >> 18);
    float lo = scal[b * 4 + 0], hi = scal[b * 4 + 1];
    float inv = 1.0f / (hi - lo + EPSC);
    float v[8]; ld8h(xb + i, v);
    float a[8];
#pragma unroll
    for (int j = 0; j < 8; ++j)
        a[j] = fminf(fmaxf((v[j] - lo) * inv, 0.f), 1.f);
    *(float4*)(nhh + i) = pk8h(a);
}

// ================= FUSED 2-ITERATION PD KERNEL =================
// Round-11/13 dataflow (75 KB LDS, global-free B-D, XCD swizzle) but 512
// threads (8 waves) per block for 2x latency hiding. `first` skips p loads.
__global__ __launch_bounds__(512) void pdf2_k(const __half* __restrict__ u,
                                              const __half* __restrict__ up,
                                              const __half* __restrict__ pxO,
                                              const __half* __restrict__ pyO,
                                              __half* __restrict__ pxN,
                                              __half* __restrict__ pyN,
                                              const __half* __restrict__ nh,
                                              const float* __restrict__ scal,
                                              __half* __restrict__ u1g,
                                              __half* __restrict__ u2g,
                                              float* __restrict__ outF,
                                              int first, int last) {
    __shared__ __align__(16) char smem[76800];              // 75 KB
    __half (*ubar0h)[512] = (__half(*)[512])smem;           // 12 rows (ph 0-A)
    __half (*py2l)[512]   = (__half(*)[512])smem;           // 9 rows (ph C+), aliases ubar0h
    __half (*u0l)[512]    = (__half(*)[512])(smem + 12288); // 12 rows (y0-2..y0+9)
    __half (*nhl)[512]    = (__half(*)[512])(smem + 24576); // 12 rows
    __half (*px1)[512]    = (__half(*)[512])(smem + 36864); // 10 rows (y0-1..y0+8)
    __half (*py1)[512]    = (__half(*)[512])(smem + 47104); // 11 rows (y0-2..y0+8)
    __half (*u1l)[512]    = (__half(*)[512])(smem + 58368); // 10 rows (y0-1..y0+8)
    __half (*px2l)[512]   = (__half(*)[512])(smem + 68608); // 8 rows  (y0..y0+7)

    int tid = threadIdx.x;
    int sub = tid >> 6, lane = tid & 63, x0 = lane * 8;     // sub in [0,8)
    int gid = blockIdx.x;                       // 0..1023
    int swz = (gid & 7) * 128 + (gid >> 3);     // bijective on [0,1024)
    int b  = swz >> 6;
    int y0 = (swz & 63) * RB;
    size_t plane = (size_t)b * NPIX;
    float sgm = fmaxf(scal[b * 4 + 2], EPSC);
    float inv = 1.0f / sgm;
    const float4 z4 = make_float4(0.f, 0.f, 0.f, 0.f);

    // ---- Phase 0: u^t (raw) + ubar^t (fp16) + nh, rows y0-2..y0+9 ----
    for (int i = sub; i < 12; i += 8) {
        int g = y0 - 2 + i;
        if (g >= 0 && g < 512) {
            size_t off = plane + (size_t)g * 512 + x0;
            float4 uraw = *(const float4*)(u + off);
            float uu[8], pp[8], ub[8];
            cvt8h(uraw, uu); ld8h(up + off, pp);
#pragma unroll
            for (int j = 0; j < 8; ++j) ub[j] = 2.f * uu[j] - pp[j];
            *(float4*)&ubar0h[i][x0] = pk8h(ub);
            *(float4*)&u0l[i][x0] = uraw;
            *(float4*)&nhl[i][x0] = *(const float4*)(nh + off);
        } else {
            *(float4*)&ubar0h[i][x0] = z4;
            *(float4*)&u0l[i][x0] = z4;
            *(float4*)&nhl[i][x0] = z4;
        }
    }
    __syncthreads();

    // ---- Phase A: p^{t+1}: py1 rows y0-2..y0+8 (c=0..10), px1 rows y0-1..y0+8 ----
    for (int c = sub; c < 11; c += 8) {
        int g = y0 - 2 + c;
        if (g >= 0 && g < 512) {
            size_t off = plane + (size_t)g * 512 + x0;
            float nhc[8], nhd[8], ubc[8], ubd[8];
            ld8h(&nhl[c][x0], nhc);
            ld8h(&nhl[c + 1][x0], nhd);
            ld8h(&ubar0h[c][x0], ubc);
            ld8h(&ubar0h[c + 1][x0], ubd);
            float nhRr = (lane < 63) ? __half2float(nhl[c][x0 + 8]) : 0.f;
            float ubRr = (lane < 63) ? __half2float(ubar0h[c][x0 + 8]) : 0.f;
            bool rD = (g < 511);
            float py0v[8] = {0,0,0,0,0,0,0,0};
            if (!first) ld8h(pyO + off, py0v);
            float pyv[8];
#pragma unroll
            for (int j = 0; j < 8; ++j) {
                float by = bnd(rD ? (nhd[j] - nhc[j]) : 0.f, inv);
                float dy = rD ? (ubd[j] - ubc[j]) : 0.f;
                pyv[j] = clmp(py0v[j] + SIG * dy, by);
            }
            *(float4*)&py1[c][x0] = pk8h(pyv);
            if (c >= 1) {
                float px0v[8] = {0,0,0,0,0,0,0,0};
                if (!first) ld8h(pxO + off, px0v);
                float pxv[8];
#pragma unroll
                for (int j = 0; j < 8; ++j) {
                    int x = x0 + j;
                    bool xok = (x < 511);
                    float nhr = (j < 7) ? nhc[j + 1] : nhRr;
                    float ubr = (j < 7) ? ubc[j + 1] : ubRr;
                    float bx = bnd(xok ? (nhr - nhc[j]) : 0.f, inv);
                    float dx = xok ? (ubr - ubc[j]) : 0.f;
                    pxv[j] = clmp(px0v[j] + SIG * dx, bx);
                }
                *(float4*)&px1[c - 1][x0] = pk8h(pxv);
            }
        } else {
            *(float4*)&py1[c][x0] = z4;
            if (c >= 1) *(float4*)&px1[c - 1][x0] = z4;
        }
    }
    __syncthreads();

    // ---- Phase B: u^{t+1} rows y0-1..y0+8 (a=0..9) -> u1l; interior -> u1g ----
    for (int a = sub; a < 10; a += 8) {
        int g = y0 - 1 + a;
        if (g >= 0 && g < 512) {
            float u0v[8]; ld8h(&u0l[a + 1][x0], u0v);
            float nhc[8];  ld8h(&nhl[a + 1][x0], nhc);
            float px1c[8]; ld8h(&px1[a][x0], px1c);
            float py1c[8]; ld8h(&py1[a + 1][x0], py1c);
            float py1u[8]; ld8h(&py1[a][x0], py1u);
            float pxl = (x0 > 0) ? __half2float(px1[a][x0 - 1]) : 0.f;
            bool gU = (g > 0);
            float uv[8];
#pragma unroll
            for (int j = 0; j < 8; ++j) {
                int x = x0 + j;
                float left = (x > 0) ? ((j > 0) ? px1c[j - 1] : pxl) : 0.f;
                float div = px1c[j] - left + py1c[j] - (gU ? py1u[j] : 0.f);
                uv[j] = (u0v[j] + TAUC * div + TAUC * nhc[j]) * IVT;
            }
            float4 packed = pk8h(uv);
            *(float4*)&u1l[a][x0] = packed;
            if (!last && g >= y0 && g < y0 + RB) {
                size_t off = plane + (size_t)g * 512 + x0;
                *(float4*)(u1g + off) = packed;
            }
        } else {
            *(float4*)&u1l[a][x0] = z4;
        }
    }
    __syncthreads();

    // ---- Phase C: p^{t+2}: py2 rows y0-1..y0+7 (e=0..8), px2 rows y0..y0+7 ----
    // (py2l aliases ubar0h, dead since the barrier after phase A)
    for (int e = sub; e < 9; e += 8) {
        int g = y0 - 1 + e;
        if (g >= 0) {                      // g <= 511 always here
            size_t off = plane + (size_t)g * 512 + x0;
            float u1c[8], u0c[8], u1d[8], u0d[8];
            ld8h(&u1l[e][x0], u1c);     ld8h(&u0l[e + 1][x0], u0c);
            ld8h(&u1l[e + 1][x0], u1d); ld8h(&u0l[e + 2][x0], u0d);
            float nhc[8], nhd[8];
            ld8h(&nhl[e + 1][x0], nhc); ld8h(&nhl[e + 2][x0], nhd);
            float ubc[8], ubd[8];
#pragma unroll
            for (int j = 0; j < 8; ++j) {
                ubc[j] = 2.f * u1c[j] - u0c[j];
                ubd[j] = 2.f * u1d[j] - u0d[j];
            }
            float ubRr = (lane < 63) ? (2.f * __half2float(u1l[e][x0 + 8]) - __half2float(u0l[e + 1][x0 + 8])) : 0.f;
            float nhRr = (lane < 63) ? __half2float(nhl[e + 1][x0 + 8]) : 0.f;
            bool rD = (g < 511);
            float py1c[8]; ld8h(&py1[e + 1][x0], py1c);
            float pyv[8];
#pragma unroll
            for (int j = 0; j < 8; ++j) {
                float by = bnd(rD ? (nhd[j] - nhc[j]) : 0.f, inv);
                float dy = rD ? (ubd[j] - ubc[j]) : 0.f;
                pyv[j] = clmp(py1c[j] + SIG * dy, by);
            }
            float4 pyp = pk8h(pyv);
            *(float4*)&py2l[e][x0] = pyp;
            if (!last && g >= y0) *(float4*)(pyN + off) = pyp;
            if (e >= 1) {
                float px1c[8]; ld8h(&px1[e][x0], px1c);
                float pxv[8];
#pragma unroll
                for (int j = 0; j < 8; ++j) {
                    int x = x0 + j;
                    bool xok = (x < 511);
                    float nhr = (j < 7) ? nhc[j + 1] : nhRr;
                    float ubr = (j < 7) ? ubc[j + 1] : ubRr;
                    float bx = bnd(xok ? (nhr - nhc[j]) : 0.f, inv);
                    float dx = xok ? (ubr - ubc[j]) : 0.f;
                    pxv[j] = clmp(px1c[j] + SIG * dx, bx);
                }
                float4 pxp = pk8h(pxv);
                *(float4*)&px2l[e - 1][x0] = pxp;
                if (!last) *(float4*)(pxN + off) = pxp;
            }
        } else {
            *(float4*)&py2l[e][x0] = z4;
        }
    }
    __syncthreads();

    // ---- Phase D: u^{t+2} rows y0..y0+7 ----
    for (int d = sub; d < 8; d += 8) {
        int g = y0 + d;
        size_t off = plane + (size_t)g * 512 + x0;
        float px2c[8]; ld8h(&px2l[d][x0], px2c);
        float py2c[8]; ld8h(&py2l[d + 1][x0], py2c);
        float py2u[8]; ld8h(&py2l[d][x0], py2u);
        float pxl = (x0 > 0) ? __half2float(px2l[d][x0 - 1]) : 0.f;
        float u1c[8]; ld8h(&u1l[d + 1][x0], u1c);
        float nhc[8]; ld8h(&nhl[d + 2][x0], nhc);
        bool gU = (g > 0);
        float uv[8];
#pragma unroll
        for (int j = 0; j < 8; ++j) {
            int x = x0 + j;
            float left = (x > 0) ? ((j > 0) ? px2c[j - 1] : pxl) : 0.f;
            float div = px2c[j] - left + py2c[j] - (gU ? py2u[j] : 0.f);
            uv[j] = (u1c[j] + TAUC * div + TAUC * nhc[j]) * IVT;
        }
        if (last) {
            float4 o0, o1;
            o0.x = fminf(fmaxf(uv[0], 0.f), 1.f);
            o0.y = fminf(fmaxf(uv[1], 0.f), 1.f);
            o0.z = fminf(fmaxf(uv[2], 0.f), 1.f);
            o0.w = fminf(fmaxf(uv[3], 0.f), 1.f);
            o1.x = fminf(fmaxf(uv[4], 0.f), 1.f);
            o1.y = fminf(fmaxf(uv[5], 0.f), 1.f);
            o1.z = fminf(fmaxf(uv[6], 0.f), 1.f);
            o1.w = fminf(fmaxf(uv[7], 0.f), 1.f);
            *(float4*)(outF + off)     = o0;
            *(float4*)(outF + off + 4) = o1;
        } else {
            *(float4*)(u2g + off) = pk8h(uv);
        }
    }
}

extern "C" void kernel_launch(void* const* d_in, const int* in_sizes, int n_in,
                              void* d_out, int out_size, void* d_ws, size_t ws_size,
                              hipStream_t stream) {
    const float* Iy = (const float*)d_in[0];
    float* out = (float*)d_out;

    dim3 hist_g(HSUB, 16);

    // layout (half units on hb):
    // 0:nhh | NP..5NP: HA..HD | 5NP..9NP: pxA,pyA,pxB,pyB | 9NP: xbh | 10NP..12NP: Hh | 12NP: hist,scal
    __half* hb  = (__half*)d_ws;
    __half* nhh = hb;
    __half* HA  = hb + (size_t)NP;
    __half* HB  = hb + (size_t)2 * NP;
    __half* HC  = hb + (size_t)3 * NP;
    __half* HD  = hb + (size_t)4 * NP;
    __half* pxA = hb + (size_t)5 * NP;
    __half* pyA = hb + (size_t)6 * NP;
    __half* pxB = hb + (size_t)7 * NP;
    __half* pyB = hb + (size_t)8 * NP;
    __half* xbh = hb + (size_t)9 * NP;
    __half* Hh  = hb + (size_t)10 * NP;      // 2 planes (hpass out)
    __half* Vh  = hb + (size_t)1 * NP;       // 2 planes (vpass out; HA..HB region, free now)
    int*    hist = (int*)(hb + (size_t)12 * NP);
    float*  scal = (float*)(hist + 16 * NBINS);

    // 1. separable 31x31 max pool (R and M=max(G,B)) + Dmip combine
    hpass3_k<<<dim3(64, 32), dim3(512), 0, stream>>>(Iy, Hh);
    vpass2h_k<<<dim3(8, 17, 32), dim3(64), 0, stream>>>(Hh, Vh);
    combineh_k<<<NP / 2048, 256, 0, stream>>>(Vh, Iy, xbh);

    // 2. robust normalize -> fp16 N_hat
    hipMemsetAsync(hist, 0, 16 * NBINS * sizeof(int), stream);
    hist2_k<<<hist_g, 1024, 0, stream>>>(xbh, hist);
    quant2_k<<<16, 1024, 0, stream>>>(hist, scal, 0.01f, 0.99f, 0, 1);
    nhat2h_k<<<NP / 2048, 256, 0, stream>>>(xbh, scal, nhh);

    // 3. sigma (median grad mag)
    hipMemsetAsync(hist, 0, 16 * NBINS * sizeof(int), stream);
    gradhisth_k<<<hist_g, 1024, 0, stream>>>(nhh, hist);
    quant2_k<<<16, 1024, 0, stream>>>(hist, scal, 0.5f, 0.5f, 2, -1);

    // 4. 15 fused launches x 2 PD iterations (u_bar = 2u - u_prev)
    //    launch 0 treats px/py as zero (first=1) -> no memset needed.
    const __half* ucur = nhh;
    const __half* uprev = nhh;
    __half* pxs[2] = {pxA, pxB};
    __half* pys[2] = {pyA, pyB};
    for (int k = 0; k < 15; ++k) {
        int cur = k & 1;
        __half* u1o = (k & 1) ? HC : HA;
        __half* u2o = (k & 1) ? HD : HB;
        pdf2_k<<<dim3(1024), 512, 0, stream>>>(ucur, uprev,
                                               pxs[cur], pys[cur],
                                               pxs[cur ^ 1], pys[cur ^ 1],
                                               nhh, scal, u1o, u2o, out,
                                               (k == 0) ? 1 : 0,
                                               (k == 14) ? 1 : 0);
        uprev = u1o;
        ucur = u2o;
    }
    // k=14 wrote clipped fp32 result directly to out.
}

// Round 15
// 424.569 us; speedup vs baseline: 1.1721x; 1.0146x over previous
//
#include <hip/hip_runtime.h>
#include <hip/hip_bf16.h>
#include <hip/hip_fp16.h>
#include <math.h>

#define NPIX   262144          // 512*512
#define NP     4194304         // 16*512*512
#define NBINS  8192
#define HSUB   16
#define RB     4               // output rows per block in fused PD kernel
#define SIG    0.125f
#define TAUC   0.125f
#define ALPHAC 0.15f
#define MUC    10.0f
#define EPSC   1e-6f
#define NEGINF -3.4e38f
#define IVT    (1.0f / (1.0f + TAUC))

// ---------- helpers ----------
__device__ __forceinline__ void cvt8h(float4 raw, float* d) {
    const __half2* h = (const __half2*)&raw;
#pragma unroll
    for (int j = 0; j < 4; ++j) {
        float2 f = __half22float2(h[j]);
        d[2 * j] = f.x; d[2 * j + 1] = f.y;
    }
}
__device__ __forceinline__ void ld8h(const __half* p, float* d) {
    cvt8h(*(const float4*)p, d);
}
__device__ __forceinline__ float4 pk8h(const float* s) {
    float4 r; __half2* h = (__half2*)&r;
#pragma unroll
    for (int j = 0; j < 4; ++j) h[j] = __floats2half2_rn(s[2 * j], s[2 * j + 1]);
    return r;
}
__device__ __forceinline__ float bnd(float d, float inv) {
    return ALPHAC * (1.f + MUC * __expf(-fabsf(d) * inv));
}
__device__ __forceinline__ float clmp(float v, float b) {
    return fminf(fmaxf(v, -b), b);
}

// ================= POOLING =================

// horizontal 31-max, 3-phase vHGW; fp16 output.
__global__ __launch_bounds__(512) void hpass3_k(const float* __restrict__ Iy,
                                                __half* __restrict__ H) {
    __shared__ float rowbuf[8][512];
    __shared__ float PB[8][512];
    __shared__ float SB[8][512];
    int tid = threadIdx.x;
    int plane = blockIdx.y;
    int y0 = blockIdx.x * 8;

#pragma unroll
    for (int q = 0; q < 2; ++q) {
        int idx = q * 512 + tid;
        int r = idx >> 7;
        int x4 = (idx & 127) << 2;
        float4 v;
        if (plane < 16) {
            v = *(const float4*)(Iy + (size_t)(plane * 3) * NPIX + (size_t)(y0 + r) * 512 + x4);
        } else {
            int b = plane - 16;
            float4 g = *(const float4*)(Iy + ((size_t)(b * 3) + 1) * NPIX + (size_t)(y0 + r) * 512 + x4);
            float4 bb = *(const float4*)(Iy + ((size_t)(b * 3) + 2) * NPIX + (size_t)(y0 + r) * 512 + x4);
            v = make_float4(fmaxf(g.x, bb.x), fmaxf(g.y, bb.y), fmaxf(g.z, bb.z), fmaxf(g.w, bb.w));
        }
        *(float4*)(&rowbuf[r][x4]) = v;
    }
    __syncthreads();

    if (tid < 272) {
        int type = tid / 136;
        int rem = tid % 136;
        int r = rem / 17;
        int seg = rem % 17;
        int s0 = seg * 31;
        if (type == 0) {
            float run = rowbuf[r][s0];
            PB[r][s0] = run;
            for (int j = 1; j < 31; ++j) {
                int idx = s0 + j;
                if (idx < 512) { run = fmaxf(run, rowbuf[r][idx]); PB[r][idx] = run; }
            }
        } else {
            int s1 = min(s0 + 30, 511);
            float run = rowbuf[r][s1];
            SB[r][s1] = run;
            for (int j = s1 - 1; j >= s0; --j) { run = fmaxf(run, rowbuf[r][j]); SB[r][j] = run; }
        }
    }
    __syncthreads();

    int x = tid, a = x - 15, bc = x + 15;
#pragma unroll
    for (int r = 0; r < 8; ++r) {
        float o;
        if (a < 0)        o = PB[r][bc];
        else if (bc > 511) o = fmaxf(SB[r][a], PB[r][511]);
        else              o = fmaxf(SB[r][a], PB[r][bc]);
        H[(size_t)plane * NPIX + (size_t)(y0 + r) * 512 + x] = __float2half_rn(o);
    }
}

// vertical 31-max, one plane x one segment per block. grid (8, 17, 32), block 64.
__global__ __launch_bounds__(64) void vpass2h_k(const __half* __restrict__ H,
                                                __half* __restrict__ V) {
    int x = blockIdx.x * 64 + threadIdx.x;
    int s = blockIdx.y;                 // 0..16
    const __half* in = H + (size_t)blockIdx.z * NPIX;
    __half*      out = V + (size_t)blockIdx.z * NPIX;
    int s0 = s * 31;

    float Sprev[31];
    if (s > 0) {
        int p0 = s0 - 31;
        float v[31];
#pragma unroll
        for (int j = 0; j < 31; ++j) v[j] = __half2float(in[(size_t)(p0 + j) * 512 + x]);
        float acc = NEGINF;
#pragma unroll
        for (int j = 30; j >= 0; --j) { acc = fmaxf(acc, v[j]); Sprev[j] = acc; }
    } else {
#pragma unroll
        for (int j = 0; j < 31; ++j) Sprev[j] = NEGINF;
    }

    float P = NEGINF;
#pragma unroll
    for (int r = 0; r < 31; ++r) {
        float vv = (s0 + r < 512) ? __half2float(in[(size_t)(s0 + r) * 512 + x]) : NEGINF;
        P = fmaxf(P, vv);
        int i = s0 + r - 15;
        if (i >= 0 && i <= 511) {
            int a = s0 + r - 30;
            float o;
            if (a < 0)       o = P;
            else if (r == 30) o = P;
            else              o = fmaxf(Sprev[r + 1], P);
            out[(size_t)i * 512 + x] = __float2half_rn(o);
        }
    }
}

// combine: xb = |vR - vM| + R, 8 px/thread
__global__ __launch_bounds__(256) void combineh_k(const __half* __restrict__ V,
                                                  const float* __restrict__ Iy,
                                                  __half* __restrict__ xb) {
    size_t i = ((size_t)blockIdx.x * 256 + threadIdx.x) * 8;
    int b = (int)(i >> 18);
    size_t off = i & (NPIX - 1);
    float vr[8], vm[8];
    ld8h(V + (size_t)b * NPIX + off, vr);
    ld8h(V + (size_t)(16 + b) * NPIX + off, vm);
    const float* R = Iy + (size_t)(b * 3) * NPIX + off;
    float4 r0 = *(const float4*)R;
    float4 r1 = *(const float4*)(R + 4);
    float rr[8] = {r0.x, r0.y, r0.z, r0.w, r1.x, r1.y, r1.z, r1.w};
    float a[8];
#pragma unroll
    for (int j = 0; j < 8; ++j) a[j] = fabsf(vr[j] - vm[j]) + rr[j];
    *(float4*)(xb + i) = pk8h(a);
}

// ================= HISTOGRAM / QUANTILE =================

__global__ __launch_bounds__(1024) void hist2_k(const __half* __restrict__ v,
                                                int* __restrict__ hist) {
    __shared__ int lh[NBINS];
    int s = blockIdx.x, b = blockIdx.y, tid = threadIdx.x;
    for (int i = tid; i < NBINS; i += 1024) lh[i] = 0;
    __syncthreads();
    const __half* p = v + (size_t)b * NPIX + (size_t)s * (NPIX / HSUB);
    for (int i = tid; i < NPIX / HSUB; i += 1024) {
        int bin = (int)(__half2float(p[i]) * (NBINS * 0.5f));
        bin = min(max(bin, 0), NBINS - 1);
        atomicAdd(&lh[bin], 1);
    }
    __syncthreads();
    for (int i = tid; i < NBINS; i += 1024) {
        int c = lh[i];
        if (c) atomicAdd(&hist[b * NBINS + i], c);
    }
}

__global__ __launch_bounds__(1024) void gradhisth_k(const __half* __restrict__ nh,
                                                    int* __restrict__ hist) {
    __shared__ int lh[NBINS];
    int s = blockIdx.x, b = blockIdx.y, tid = threadIdx.x;
    for (int i = tid; i < NBINS; i += 1024) lh[i] = 0;
    __syncthreads();
    const __half* p = nh + (size_t)b * NPIX;
    int base = s * (NPIX / HSUB);
    for (int ii = tid; ii < NPIX / HSUB; ii += 1024) {
        int i = base + ii;
        float c = __half2float(p[i]);
        int x = i & 511, y = i >> 9;
        float dx = (x < 511) ? __half2float(p[i + 1])   - c : 0.f;
        float dy = (y < 511) ? __half2float(p[i + 512]) - c : 0.f;
        float gm = sqrtf(dx * dx + dy * dy + EPSC);
        int bin = (int)(gm * (NBINS * 0.5f));
        bin = min(max(bin, 0), NBINS - 1);
        atomicAdd(&lh[bin], 1);
    }
    __syncthreads();
    for (int i = tid; i < NBINS; i += 1024) {
        int c = lh[i];
        if (c) atomicAdd(&hist[b * NBINS + i], c);
    }
}

__global__ __launch_bounds__(1024) void quant2_k(const int* __restrict__ hist,
                                                 float* __restrict__ scal,
                                                 float q0, float q1, int s0, int s1) {
    __shared__ int csum[1025];
    __shared__ int wsum[16];
    int b = blockIdx.x, tid = threadIdx.x;
    const int* h = hist + b * NBINS;
    int s = 0;
#pragma unroll
    for (int j = 0; j < NBINS / 1024; ++j) s += h[tid * (NBINS / 1024) + j];

    int lane = tid & 63, wave = tid >> 6;
    int v = s;
#pragma unroll
    for (int off = 1; off < 64; off <<= 1) {
        int n = __shfl_up(v, off, 64);
        if (lane >= off) v += n;
    }
    if (lane == 63) wsum[wave] = v;
    __syncthreads();
    if (wave == 0 && lane < 16) {
        int w = wsum[lane];
#pragma unroll
        for (int off = 1; off < 16; off <<= 1) {
            int n = __shfl_up(w, off, 64);
            if (lane >= off) w += n;
        }
        wsum[lane] = w;
    }
    __syncthreads();
    int incl = v + (wave > 0 ? wsum[wave - 1] : 0);
    csum[tid + 1] = incl;
    if (tid == 0) csum[0] = 0;
    __syncthreads();

#pragma unroll
    for (int pass = 0; pass < 2; ++pass) {
        int slot = pass ? s1 : s0;
        if (slot < 0) continue;
        float q = pass ? q1 : q0;
        float t = q * (float)(NPIX - 1);
        if ((float)csum[tid] <= t && (float)csum[tid + 1] > t) {
            const int per = NBINS / 1024;
            int cb = csum[tid];
            int bin = tid * per;
            int hv = 1;
            for (int j = 0; j < per; ++j) {
                hv = h[tid * per + j];
                if ((float)(cb + hv) > t) { bin = tid * per + j; break; }
                cb += hv;
            }
            float k = t - (float)cb;
            scal[b * 4 + slot] = ((float)bin + (k + 0.5f) / (float)hv) * (2.0f / NBINS);
        }
    }
}

// ---------------- N_hat (fp16) from xb (fp16), 8 px/thread ----------------
__global__ __launch_bounds__(256) void nhat2h_k(const __half* __restrict__ xb,
                                                const float* __restrict__ scal,
                                                __half* __restrict__ nhh) {
    size_t i = ((size_t)blockIdx.x * 256 + threadIdx.x) * 8;
    int b = (int)(i >> 18);
    float lo = scal[b * 4 + 0], hi = scal[b * 4 + 1];
    float inv = 1.0f / (hi - lo + EPSC);
    float v[8]; ld8h(xb + i, v);
    float a[8];
#pragma unroll
    for (int j = 0; j < 8; ++j)
        a[j] = fminf(fmaxf((v[j] - lo) * inv, 0.f), 1.f);
    *(float4*)(nhh + i) = pk8h(a);
}

// ================= FUSED 2-ITERATION PD KERNEL =================
// Round-13/14 dataflow, RB=4: 47 KB LDS -> 3 blocks/CU, 512 threads (8 waves),
// grid 2048, bijective XCD swizzle. Rounding points identical.
__global__ __launch_bounds__(512) void pdf2_k(const __half* __restrict__ u,
                                              const __half* __restrict__ up,
                                              const __half* __restrict__ pxO,
                                              const __half* __restrict__ pyO,
                                              __half* __restrict__ pxN,
                                              __half* __restrict__ pyN,
                                              const __half* __restrict__ nh,
                                              const float* __restrict__ scal,
                                              __half* __restrict__ u1g,
                                              __half* __restrict__ u2g,
                                              float* __restrict__ outF,
                                              int first, int last) {
    __shared__ __align__(16) char smem[48128];              // 47 KB
    __half (*ubar0h)[512] = (__half(*)[512])smem;           // 8 rows (ph 0-A)
    __half (*py2l)[512]   = (__half(*)[512])smem;           // 5 rows (ph C+), aliases ubar0h
    __half (*u0l)[512]    = (__half(*)[512])(smem + 8192);  // 8 rows (y0-2..y0+5)
    __half (*nhl)[512]    = (__half(*)[512])(smem + 16384); // 8 rows
    __half (*px1)[512]    = (__half(*)[512])(smem + 24576); // 6 rows (y0-1..y0+4)
    __half (*py1)[512]    = (__half(*)[512])(smem + 30720); // 7 rows (y0-2..y0+4)
    __half (*u1l)[512]    = (__half(*)[512])(smem + 37888); // 6 rows (y0-1..y0+4)
    __half (*px2l)[512]   = (__half(*)[512])(smem + 44032); // 4 rows (y0..y0+3)

    int tid = threadIdx.x;
    int sub = tid >> 6, lane = tid & 63, x0 = lane * 8;     // sub in [0,8)
    int gid = blockIdx.x;                       // 0..2047
    int swz = (gid & 7) * 256 + (gid >> 3);     // bijective on [0,2048)
    int b  = swz >> 7;                          // 128 tiles per batch
    int y0 = (swz & 127) * RB;
    size_t plane = (size_t)b * NPIX;
    float sgm = fmaxf(scal[b * 4 + 2], EPSC);
    float inv = 1.0f / sgm;
    const float4 z4 = make_float4(0.f, 0.f, 0.f, 0.f);

    // ---- Phase 0: u^t (raw) + ubar^t (fp16) + nh, rows y0-2..y0+5 ----
    for (int i = sub; i < 8; i += 8) {
        int g = y0 - 2 + i;
        if (g >= 0 && g < 512) {
            size_t off = plane + (size_t)g * 512 + x0;
            float4 uraw = *(const float4*)(u + off);
            float uu[8], pp[8], ub[8];
            cvt8h(uraw, uu); ld8h(up + off, pp);
#pragma unroll
            for (int j = 0; j < 8; ++j) ub[j] = 2.f * uu[j] - pp[j];
            *(float4*)&ubar0h[i][x0] = pk8h(ub);
            *(float4*)&u0l[i][x0] = uraw;
            *(float4*)&nhl[i][x0] = *(const float4*)(nh + off);
        } else {
            *(float4*)&ubar0h[i][x0] = z4;
            *(float4*)&u0l[i][x0] = z4;
            *(float4*)&nhl[i][x0] = z4;
        }
    }
    __syncthreads();

    // ---- Phase A: p^{t+1}: py1 rows y0-2..y0+4 (c=0..6), px1 rows y0-1..y0+4 ----
    for (int c = sub; c < 7; c += 8) {
        int g = y0 - 2 + c;
        if (g >= 0 && g < 512) {
            size_t off = plane + (size_t)g * 512 + x0;
            float nhc[8], nhd[8], ubc[8], ubd[8];
            ld8h(&nhl[c][x0], nhc);
            ld8h(&nhl[c + 1][x0], nhd);
            ld8h(&ubar0h[c][x0], ubc);
            ld8h(&ubar0h[c + 1][x0], ubd);
            float nhRr = (lane < 63) ? __half2float(nhl[c][x0 + 8]) : 0.f;
            float ubRr = (lane < 63) ? __half2float(ubar0h[c][x0 + 8]) : 0.f;
            bool rD = (g < 511);
            float py0v[8] = {0,0,0,0,0,0,0,0};
            if (!first) ld8h(pyO + off, py0v);
            float pyv[8];
#pragma unroll
            for (int j = 0; j < 8; ++j) {
                float by = bnd(rD ? (nhd[j] - nhc[j]) : 0.f, inv);
                float dy = rD ? (ubd[j] - ubc[j]) : 0.f;
                pyv[j] = clmp(py0v[j] + SIG * dy, by);
            }
            *(float4*)&py1[c][x0] = pk8h(pyv);
            if (c >= 1) {
                float px0v[8] = {0,0,0,0,0,0,0,0};
                if (!first) ld8h(pxO + off, px0v);
                float pxv[8];
#pragma unroll
                for (int j = 0; j < 8; ++j) {
                    int x = x0 + j;
                    bool xok = (x < 511);
                    float nhr = (j < 7) ? nhc[j + 1] : nhRr;
                    float ubr = (j < 7) ? ubc[j + 1] : ubRr;
                    float bx = bnd(xok ? (nhr - nhc[j]) : 0.f, inv);
                    float dx = xok ? (ubr - ubc[j]) : 0.f;
                    pxv[j] = clmp(px0v[j] + SIG * dx, bx);
                }
                *(float4*)&px1[c - 1][x0] = pk8h(pxv);
            }
        } else {
            *(float4*)&py1[c][x0] = z4;
            if (c >= 1) *(float4*)&px1[c - 1][x0] = z4;
        }
    }
    __syncthreads();

    // ---- Phase B: u^{t+1} rows y0-1..y0+4 (a=0..5) -> u1l; interior -> u1g ----
    for (int a = sub; a < 6; a += 8) {
        int g = y0 - 1 + a;
        if (g >= 0 && g < 512) {
            float u0v[8]; ld8h(&u0l[a + 1][x0], u0v);
            float nhc[8];  ld8h(&nhl[a + 1][x0], nhc);
            float px1c[8]; ld8h(&px1[a][x0], px1c);
            float py1c[8]; ld8h(&py1[a + 1][x0], py1c);
            float py1u[8]; ld8h(&py1[a][x0], py1u);
            float pxl = (x0 > 0) ? __half2float(px1[a][x0 - 1]) : 0.f;
            bool gU = (g > 0);
            float uv[8];
#pragma unroll
            for (int j = 0; j < 8; ++j) {
                int x = x0 + j;
                float left = (x > 0) ? ((j > 0) ? px1c[j - 1] : pxl) : 0.f;
                float div = px1c[j] - left + py1c[j] - (gU ? py1u[j] : 0.f);
                uv[j] = (u0v[j] + TAUC * div + TAUC * nhc[j]) * IVT;
            }
            float4 packed = pk8h(uv);
            *(float4*)&u1l[a][x0] = packed;
            if (!last && g >= y0 && g < y0 + RB) {
                size_t off = plane + (size_t)g * 512 + x0;
                *(float4*)(u1g + off) = packed;
            }
        } else {
            *(float4*)&u1l[a][x0] = z4;
        }
    }
    __syncthreads();

    // ---- Phase C: p^{t+2}: py2 rows y0-1..y0+3 (e=0..4), px2 rows y0..y0+3 ----
    // (py2l aliases ubar0h, dead since the barrier after phase A)
    for (int e = sub; e < 5; e += 8) {
        int g = y0 - 1 + e;
        if (g >= 0) {                      // g <= 511 always here
            size_t off = plane + (size_t)g * 512 + x0;
            float u1c[8], u0c[8], u1d[8], u0d[8];
            ld8h(&u1l[e][x0], u1c);     ld8h(&u0l[e + 1][x0], u0c);
            ld8h(&u1l[e + 1][x0], u1d); ld8h(&u0l[e + 2][x0], u0d);
            float nhc[8], nhd[8];
            ld8h(&nhl[e + 1][x0], nhc); ld8h(&nhl[e + 2][x0], nhd);
            float ubc[8], ubd[8];
#pragma unroll
            for (int j = 0; j < 8; ++j) {
                ubc[j] = 2.f * u1c[j] - u0c[j];
                ubd[j] = 2.f * u1d[j] - u0d[j];
            }
            float ubRr = (lane < 63) ? (2.f * __half2float(u1l[e][x0 + 8]) - __half2float(u0l[e + 1][x0 + 8])) : 0.f;
            float nhRr = (lane < 63) ? __half2float(nhl[e + 1][x0 + 8]) : 0.f;
            bool rD = (g < 511);
            float py1c[8]; ld8h(&py1[e + 1][x0], py1c);
            float pyv[8];
#pragma unroll
            for (int j = 0; j < 8; ++j) {
                float by = bnd(rD ? (nhd[j] - nhc[j]) : 0.f, inv);
                float dy = rD ? (ubd[j] - ubc[j]) : 0.f;
                pyv[j] = clmp(py1c[j] + SIG * dy, by);
            }
            float4 pyp = pk8h(pyv);
            *(float4*)&py2l[e][x0] = pyp;
            if (!last && g >= y0) *(float4*)(pyN + off) = pyp;
            if (e >= 1) {
                float px1c[8]; ld8h(&px1[e][x0], px1c);
                float pxv[8];
#pragma unroll
                for (int j = 0; j < 8; ++j) {
                    int x = x0 + j;
                    bool xok = (x < 511);
                    float nhr = (j < 7) ? nhc[j + 1] : nhRr;
                    float ubr = (j < 7) ? ubc[j + 1] : ubRr;
                    float bx = bnd(xok ? (nhr - nhc[j]) : 0.f, inv);
                    float dx = xok ? (ubr - ubc[j]) : 0.f;
                    pxv[j] = clmp(px1c[j] + SIG * dx, bx);
                }
                float4 pxp = pk8h(pxv);
                *(float4*)&px2l[e - 1][x0] = pxp;
                if (!last) *(float4*)(pxN + off) = pxp;
            }
        } else {
            *(float4*)&py2l[e][x0] = z4;
        }
    }
    __syncthreads();

    // ---- Phase D: u^{t+2} rows y0..y0+3 ----
    for (int d = sub; d < 4; d += 8) {
        int g = y0 + d;
        size_t off = plane + (size_t)g * 512 + x0;
        float px2c[8]; ld8h(&px2l[d][x0], px2c);
        float py2c[8]; ld8h(&py2l[d + 1][x0], py2c);
        float py2u[8]; ld8h(&py2l[d][x0], py2u);
        float pxl = (x0 > 0) ? __half2float(px2l[d][x0 - 1]) : 0.f;
        float u1c[8]; ld8h(&u1l[d + 1][x0], u1c);
        float nhc[8]; ld8h(&nhl[d + 2][x0], nhc);
        bool gU = (g > 0);
        float uv[8];
#pragma unroll
        for (int j = 0; j < 8; ++j) {
            int x = x0 + j;
            float left = (x > 0) ? ((j > 0) ? px2c[j - 1] : pxl) : 0.f;
            float div = px2c[j] - left + py2c[j] - (gU ? py2u[j] : 0.f);
            uv[j] = (u1c[j] + TAUC * div + TAUC * nhc[j]) * IVT;
        }
        if (last) {
            float4 o0, o1;
            o0.x = fminf(fmaxf(uv[0], 0.f), 1.f);
            o0.y = fminf(fmaxf(uv[1], 0.f), 1.f);
            o0.z = fminf(fmaxf(uv[2], 0.f), 1.f);
            o0.w = fminf(fmaxf(uv[3], 0.f), 1.f);
            o1.x = fminf(fmaxf(uv[4], 0.f), 1.f);
            o1.y = fminf(fmaxf(uv[5], 0.f), 1.f);
            o1.z = fminf(fmaxf(uv[6], 0.f), 1.f);
            o1.w = fminf(fmaxf(uv[7], 0.f), 1.f);
            *(float4*)(outF + off)     = o0;
            *(float4*)(outF + off + 4) = o1;
        } else {
            *(float4*)(u2g + off) = pk8h(uv);
        }
    }
}

extern "C" void kernel_launch(void* const* d_in, const int* in_sizes, int n_in,
                              void* d_out, int out_size, void* d_ws, size_t ws_size,
                              hipStream_t stream) {
    const float* Iy = (const float*)d_in[0];
    float* out = (float*)d_out;

    dim3 hist_g(HSUB, 16);

    // layout (half units on hb):
    // 0:nhh | NP..5NP: HA..HD | 5NP..9NP: pxA,pyA,pxB,pyB | 9NP: xbh | 10NP..12NP: Hh | 12NP: hist,scal
    __half* hb  = (__half*)d_ws;
    __half* nhh = hb;
    __half* HA  = hb + (size_t)NP;
    __half* HB  = hb + (size_t)2 * NP;
    __half* HC  = hb + (size_t)3 * NP;
    __half* HD  = hb + (size_t)4 * NP;
    __half* pxA = hb + (size_t)5 * NP;
    __half* pyA = hb + (size_t)6 * NP;
    __half* pxB = hb + (size_t)7 * NP;
    __half* pyB = hb + (size_t)8 * NP;
    __half* xbh = hb + (size_t)9 * NP;
    __half* Hh  = hb + (size_t)10 * NP;      // 2 planes (hpass out)
    __half* Vh  = hb + (size_t)1 * NP;       // 2 planes (vpass out; HA..HB region, free now)
    int*    hist = (int*)(hb + (size_t)12 * NP);
    float*  scal = (float*)(hist + 16 * NBINS);

    // 1. separable 31x31 max pool (R and M=max(G,B)) + Dmip combine
    hpass3_k<<<dim3(64, 32), dim3(512), 0, stream>>>(Iy, Hh);
    vpass2h_k<<<dim3(8, 17, 32), dim3(64), 0, stream>>>(Hh, Vh);
    combineh_k<<<NP / 2048, 256, 0, stream>>>(Vh, Iy, xbh);

    // 2. robust normalize -> fp16 N_hat
    hipMemsetAsync(hist, 0, 16 * NBINS * sizeof(int), stream);
    hist2_k<<<hist_g, 1024, 0, stream>>>(xbh, hist);
    quant2_k<<<16, 1024, 0, stream>>>(hist, scal, 0.01f, 0.99f, 0, 1);
    nhat2h_k<<<NP / 2048, 256, 0, stream>>>(xbh, scal, nhh);

    // 3. sigma (median grad mag)
    hipMemsetAsync(hist, 0, 16 * NBINS * sizeof(int), stream);
    gradhisth_k<<<hist_g, 1024, 0, stream>>>(nhh, hist);
    quant2_k<<<16, 1024, 0, stream>>>(hist, scal, 0.5f, 0.5f, 2, -1);

    // 4. 15 fused launches x 2 PD iterations (u_bar = 2u - u_prev)
    //    launch 0 treats px/py as zero (first=1) -> no memset needed.
    const __half* ucur = nhh;
    const __half* uprev = nhh;
    __half* pxs[2] = {pxA, pxB};
    __half* pys[2] = {pyA, pyB};
    for (int k = 0; k < 15; ++k) {
        int cur = k & 1;
        __half* u1o = (k & 1) ? HC : HA;
        __half* u2o = (k & 1) ? HD : HB;
        pdf2_k<<<dim3(2048), 512, 0, stream>>>(ucur, uprev,
                                               pxs[cur], pys[cur],
                                               pxs[cur ^ 1], pys[cur ^ 1],
                                               nhh, scal, u1o, u2o, out,
                                               (k == 0) ? 1 : 0,
                                               (k == 14) ? 1 : 0);
        uprev = u1o;
        ucur = u2o;
    }
    // k=14 wrote clipped fp32 result directly to out.
}